// Round 6
// baseline (115.666 us; speedup 1.0000x reference)
//
#include <hip/hip_runtime.h>
#include <math.h>

#define BATCH 8
#define CINCH 256
#define CMID  128
#define NPIX  4096   // 64*64
#define MPIX  1024   // 32*32

typedef __attribute__((ext_vector_type(8))) short bf16x8;
typedef __attribute__((ext_vector_type(4))) short s16x4;
typedef __attribute__((ext_vector_type(4))) float f32x4;

static __device__ __forceinline__ short f2bf(float f) {
    unsigned u = __float_as_uint(f);
    u = (u + 0x7fffu + ((u >> 16) & 1u)) >> 16;   // RNE bf16
    return (short)u;
}

static __device__ __forceinline__ void gl16(const void* g, void* l) {
    __builtin_amdgcn_global_load_lds(
        (const __attribute__((address_space(1))) void*)g,
        (__attribute__((address_space(3))) void*)l, 16, 0, 0);
}

// ---------------------------------------------------------------------------
// Weight f32->bf16 pre-convert
// ---------------------------------------------------------------------------
__global__ __launch_bounds__(256)
void wcvt_k(const float* __restrict__ a, const float* __restrict__ b,
            const float* __restrict__ c, const float* __restrict__ d,
            short* __restrict__ o)
{
    int i = (blockIdx.x * 256 + threadIdx.x) * 4;   // 131072 total
    const float* src; int j;
    if (i < 32768)       { src = a; j = i; }
    else if (i < 65536)  { src = b; j = i - 32768; }
    else if (i < 98304)  { src = c; j = i - 65536; }
    else                 { src = d; j = i - 98304; }
    float4 v = *(const float4*)(src + j);
    s16x4 r = { f2bf(v.x), f2bf(v.y), f2bf(v.z), f2bf(v.w) };
    *(s16x4*)(o + i) = r;
}

// ---------------------------------------------------------------------------
// Fused transpose-cast + maxpool:
//   x[B,256,4096] f32 -> xT[B,4096,256] bf16, xpT[B,1024,256] bf16
// ---------------------------------------------------------------------------
__global__ __launch_bounds__(256)
void pool_transpose_k(const float* __restrict__ x, short* __restrict__ xT,
                      short* __restrict__ xpT)
{
    __shared__ float lds[128 * 65];
    const int r   = blockIdx.x;       // pooled row hp (0..31)
    const int cht = blockIdx.y;       // ch tile (0..3)
    const int b   = blockIdx.z;
    const int t   = threadIdx.x;
    const int wl  = t & 63;
    const int cq  = t >> 6;

    const float* xb = x + ((size_t)b * 256 + cht * 64) * 4096 + r * 128;
#pragma unroll
    for (int hh = 0; hh < 2; ++hh)
#pragma unroll
        for (int i = 0; i < 16; ++i) {
            int ch = cq + i * 4;
            lds[(hh * 64 + wl) * 65 + ch] = xb[(size_t)ch * 4096 + hh * 64 + wl];
        }
    __syncthreads();

    short* xTb = xT + ((size_t)b * 4096 + r * 128) * 256 + cht * 64;
#pragma unroll
    for (int j = 0; j < 32; ++j) {
        int lrow = cq * 32 + j;
        xTb[(size_t)lrow * 256 + wl] = f2bf(lds[lrow * 65 + wl]);
    }
    short* xpb = xpT + ((size_t)b * 1024 + r * 32) * 256 + cht * 64;
#pragma unroll
    for (int k = 0; k < 8; ++k) {
        int wp = cq * 8 + k;
        float v = fmaxf(fmaxf(lds[(2 * wp) * 65 + wl], lds[(2 * wp + 1) * 65 + wl]),
                        fmaxf(lds[(64 + 2 * wp) * 65 + wl], lds[(64 + 2 * wp + 1) * 65 + wl]));
        xpb[(size_t)wp * 256 + wl] = f2bf(v);
    }
}

// ---------------------------------------------------------------------------
// theta conv: 16 rows x 64 co per wave; grid (64, 2 coH, 8 b) -> 4 waves/SIMD.
// out [b][n][128] linear bf16.
// ---------------------------------------------------------------------------
__global__ __launch_bounds__(256)
void mfma_conv_th_k(const short* __restrict__ inT, const short* __restrict__ wh,
                    const float* __restrict__ bias, short* __restrict__ outp)
{
    const int t  = threadIdx.x;
    const int wv = t >> 6;
    const int l  = t & 63;
    const int lr = l & 15;
    const int lg = l >> 4;
    const int b   = blockIdx.z;
    const int coH = blockIdx.y;
    const int m0  = blockIdx.x * 64 + wv * 16;

    const short* wb = wh + (size_t)coH * 64 * 256;
    const size_t inb = ((size_t)b * NPIX) * 256 + lg * 8;

    f32x4 o[4];
#pragma unroll
    for (int dt = 0; dt < 4; ++dt)
#pragma unroll
        for (int e = 0; e < 4; ++e) o[dt][e] = 0.f;

    for (int kt = 0; kt < 8; ++kt) {
        bf16x8 a = *(const bf16x8*)(inT + inb + (size_t)(m0 + lr) * 256 + kt * 32);
#pragma unroll
        for (int dt = 0; dt < 4; ++dt) {
            bf16x8 bv = *(const bf16x8*)(wb + (size_t)(dt * 16 + lr) * 256 + kt * 32 + lg * 8);
            o[dt] = __builtin_amdgcn_mfma_f32_16x16x32_bf16(a, bv, o[dt], 0, 0, 0);
        }
    }

    float bv4[4];
#pragma unroll
    for (int dt = 0; dt < 4; ++dt) bv4[dt] = bias[coH * 64 + dt * 16 + lr];

    short* ob = outp + ((size_t)b * NPIX) * 128;
#pragma unroll
    for (int rr = 0; rr < 4; ++rr) {
        int n = m0 + lg * 4 + rr;
#pragma unroll
        for (int dt = 0; dt < 4; ++dt)
            ob[(size_t)n * 128 + coH * 64 + dt * 16 + lr] = f2bf(o[dt][rr] + bv4[dt]);
    }
}

// ---------------------------------------------------------------------------
// phi+g conv: 16 rows x 64 co per wave; grid (16, 2 coH, 16 = b*2+ep).
// phi -> frag-order chunks; G -> frag-order chunks (ch-major granules).
// ---------------------------------------------------------------------------
__global__ __launch_bounds__(256)
void mfma_conv_pg_k(const short* __restrict__ inT,
                    const short* __restrict__ wph, const float* __restrict__ pbias,
                    const short* __restrict__ wgh, const float* __restrict__ gbias,
                    short* __restrict__ phiO, short* __restrict__ gO)
{
    const int t  = threadIdx.x;
    const int wv = t >> 6;
    const int l  = t & 63;
    const int lr = l & 15;
    const int lg = l >> 4;
    const int b   = blockIdx.z >> 1;
    const int ep  = blockIdx.z & 1;
    const int coH = blockIdx.y;
    const int m0  = blockIdx.x * 64 + wv * 16;

    const short* wb = (ep ? wgh : wph) + (size_t)coH * 64 * 256;
    const float* bias = ep ? gbias : pbias;
    const size_t inb = ((size_t)b * MPIX) * 256 + lg * 8;

    f32x4 o[4];
#pragma unroll
    for (int dt = 0; dt < 4; ++dt)
#pragma unroll
        for (int e = 0; e < 4; ++e) o[dt][e] = 0.f;

    for (int kt = 0; kt < 8; ++kt) {
        bf16x8 a = *(const bf16x8*)(inT + inb + (size_t)(m0 + lr) * 256 + kt * 32);
#pragma unroll
        for (int dt = 0; dt < 4; ++dt) {
            bf16x8 bv = *(const bf16x8*)(wb + (size_t)(dt * 16 + lr) * 256 + kt * 32 + lg * 8);
            o[dt] = __builtin_amdgcn_mfma_f32_16x16x32_bf16(a, bv, o[dt], 0, 0, 0);
        }
    }

    float bv4[4];
#pragma unroll
    for (int dt = 0; dt < 4; ++dt) bv4[dt] = bias[coH * 64 + dt * 16 + lr];

    if (ep == 0) {   // phi frag-order: per element (m, cc)
        short* ob = phiO + (size_t)b * 32 * 4096;
#pragma unroll
        for (int rr = 0; rr < 4; ++rr) {
            int m = m0 + lg * 4 + rr;
            short* cb = ob + (size_t)(m >> 5) * 4096 + ((m >> 4) & 1) * 512 + (m & 15) * 8;
#pragma unroll
            for (int dt = 0; dt < 4; ++dt) {
                int cc = coH * 64 + dt * 16 + lr;
                cb[(cc >> 5) * 1024 + ((cc >> 3) & 3) * 128 + (cc & 7)]
                    = f2bf(o[dt][rr] + bv4[dt]);
            }
        }
    } else {         // G: lane's 4 accs = keys m0+lg*4+{0..3} (consecutive)
        short* cb = gO + (size_t)b * 32 * 4096 + (size_t)(m0 >> 5) * 4096;
        const int keyblk = ((m0 >> 4) & 1) * 2 + (lg >> 1);
#pragma unroll
        for (int dt = 0; dt < 4; ++dt) {
            int cc = coH * 64 + dt * 16 + lr;   // channel
            s16x4 sv;
#pragma unroll
            for (int rr = 0; rr < 4; ++rr) sv[rr] = f2bf(o[dt][rr] + bv4[dt]);
            *(s16x4*)(cb + (size_t)((cc >> 4) * 64 + keyblk * 16 + (cc & 15)) * 8
                         + (lg & 1) * 4) = sv;
        }
    }
}

// ---------------------------------------------------------------------------
// MFMA attention v6: 8 waves x 16 q-rows; triple-buffered staging with
// counted vmcnt(2) (T4) — one barrier per chunk, loads span iterations.
// ---------------------------------------------------------------------------
__global__ __launch_bounds__(512)
void attn_v6(const short* __restrict__ theta, const short* __restrict__ phi_sw,
             const short* __restrict__ G_sw, short* __restrict__ Z)
{
    __shared__ short phiL[3][4096];
    __shared__ short gL[3][4096];
    __shared__ short pl8[8][512];

    const int t  = threadIdx.x;
    const int wv = t >> 6;
    const int l  = t & 63;
    const int lr = l & 15;
    const int lg = l >> 4;
    const int bid = blockIdx.x;
    const int b   = bid & 7;            // batch -> XCD
    const int s   = bid >> 3;           // 0..31: n & 31

    const short* thb = theta + (size_t)b * NPIX * 128;
    const char*  phC = (const char*)phi_sw + (size_t)b * 32 * 8192;
    const char*  gC  = (const char*)G_sw  + (size_t)b * 32 * 8192;
    short* pl = &pl8[wv][0];

    auto STAGE = [&](int bufi, int chunk) {
        const char* ps = phC + (size_t)chunk * 8192 + wv * 1024 + l * 16;
        const char* gs = gC  + (size_t)chunk * 8192 + wv * 1024 + l * 16;
        gl16(ps, (char*)&phiL[bufi][0] + wv * 1024);
        gl16(gs, (char*)&gL[bufi][0]  + wv * 1024);
    };

    STAGE(0, 0);
    STAGE(1, 1);

    // theta B-frags: query n(j) = (wv*16 + j)*32 + s; lane j=lr
    bf16x8 bq[4];
    {
        int n = (wv * 16 + lr) * 32 + s;
#pragma unroll
        for (int kt = 0; kt < 4; ++kt)
            bq[kt] = *(const bf16x8*)(thb + (size_t)n * 128 + kt * 32 + lg * 8);
    }

    f32x4 o[8];
#pragma unroll
    for (int dt = 0; dt < 8; ++dt)
#pragma unroll
        for (int e = 0; e < 4; ++e) o[dt][e] = 0.f;
    float rm = -1e30f, ps_ = 0.f;

    for (int c = 0; c < 32; ++c) {
        // chunk c's 2 loads/lane are the oldest; chunk c+1's may stay in flight
        if (c < 31) asm volatile("s_waitcnt vmcnt(2)" ::: "memory");
        else        asm volatile("s_waitcnt vmcnt(0)" ::: "memory");
        __syncthreads();
        if (c < 30) STAGE((c + 2) % 3, c + 2);

        const int cur = c % 3;
        const char* pb = (const char*)&phiL[cur][0];
        const char* gb = (const char*)&gL[cur][0];

        // ---- S^T = mfma(A=phi rows m, B=theta rows n) -> D[key][query]
        f32x4 ssw[2];
#pragma unroll
        for (int mt = 0; mt < 2; ++mt)
#pragma unroll
            for (int e = 0; e < 4; ++e) ssw[mt][e] = 0.f;
#pragma unroll
        for (int kt = 0; kt < 4; ++kt) {
            bf16x8 a0 = *(const bf16x8*)(pb + ((kt * 2 + 0) * 64 + l) * 16);
            bf16x8 a1 = *(const bf16x8*)(pb + ((kt * 2 + 1) * 64 + l) * 16);
            ssw[0] = __builtin_amdgcn_mfma_f32_16x16x32_bf16(a0, bq[kt], ssw[0], 0, 0, 0);
            ssw[1] = __builtin_amdgcn_mfma_f32_16x16x32_bf16(a1, bq[kt], ssw[1], 0, 0, 0);
        }

        // ---- G B-frags (ch rows)
        bf16x8 gf[8];
#pragma unroll
        for (int dt = 0; dt < 8; ++dt)
            gf[dt] = *(const bf16x8*)(gb + (dt * 64 + l) * 16);

        // ---- defer-max online softmax (query col = lr)
        float cmx = fmaxf(fmaxf(fmaxf(ssw[0][0], ssw[0][1]), fmaxf(ssw[0][2], ssw[0][3])),
                          fmaxf(fmaxf(ssw[1][0], ssw[1][1]), fmaxf(ssw[1][2], ssw[1][3])));
        if (__any(cmx > rm + 8.f)) {
            float cm = cmx;
            cm = fmaxf(cm, __shfl_xor(cm, 16));
            cm = fmaxf(cm, __shfl_xor(cm, 32));
            float nm = fmaxf(rm, cm);
            float sc = __expf(rm - nm);
            ps_ *= sc;
            rm = nm;
            float scg[4];
#pragma unroll
            for (int rr = 0; rr < 4; ++rr) scg[rr] = __shfl(sc, lg * 4 + rr);
#pragma unroll
            for (int dt = 0; dt < 8; ++dt)
#pragma unroll
                for (int rr = 0; rr < 4; ++rr) o[dt][rr] *= scg[rr];
        }

        // ---- P = exp(S^T - rm): packed 8B stores, conflict-free
#pragma unroll
        for (int mt = 0; mt < 2; ++mt) {
            s16x4 pv;
#pragma unroll
            for (int rr = 0; rr < 4; ++rr) {
                float p = __expf(ssw[mt][rr] - rm);
                ps_ += p;
                pv[rr] = f2bf(p);
            }
            *(s16x4*)(pl + ((mt * 2 + (lg >> 1)) * 16 + lr) * 8 + (lg & 1) * 4) = pv;
        }

        // ---- PV: A = P (rows = queries), B = G
        bf16x8 pa = *(const bf16x8*)(pl + l * 8);
#pragma unroll
        for (int dt = 0; dt < 8; ++dt)
            o[dt] = __builtin_amdgcn_mfma_f32_16x16x32_bf16(pa, gf[dt], o[dt], 0, 0, 0);
    }

    // ---- finalize: inv per query, gathered to O rows; packed Z writes
    float tot = ps_;
    tot += __shfl_xor(tot, 16);
    tot += __shfl_xor(tot, 32);
    float inv = 1.f / tot;
    float invg[4];
#pragma unroll
    for (int rr = 0; rr < 4; ++rr) invg[rr] = __shfl(inv, lg * 4 + rr);

    short* Zb = Z + (size_t)b * 16 * 4096 * 8;
#pragma unroll
    for (int dt = 0; dt < 8; ++dt) {
        s16x4 zv;
#pragma unroll
        for (int rr = 0; rr < 4; ++rr) zv[rr] = f2bf(o[dt][rr] * invg[rr]);
        size_t g = (size_t)(wv * 2 + (lg >> 1)) * 4096 + s * 128 + dt * 16 + lr;
        *(s16x4*)(Zb + g * 8 + (lg & 1) * 4) = zv;
    }
}

// ---------------------------------------------------------------------------
// Final conv: out[b][256 co][4096 l] = wz @ m3 + bias + x. bf16 wz direct.
// ---------------------------------------------------------------------------
__global__ __launch_bounds__(256)
void conv_fin_k(const short* __restrict__ Z, const short* __restrict__ wzh,
                const float* __restrict__ wzb, const float* __restrict__ x,
                float* __restrict__ out)
{
    const int t  = threadIdx.x;
    const int wv = t >> 6;
    const int l  = t & 63;
    const int lr = l & 15;
    const int lg = l >> 4;
    const int b  = blockIdx.z;
    const int co0 = blockIdx.y * 64 + (wv >> 1) * 32;
    const int l0  = blockIdx.x * 256 + (wv & 1) * 128;

    bf16x8 afr[2][4];
#pragma unroll
    for (int nt = 0; nt < 2; ++nt) {
        int co = co0 + nt * 16 + lr;
#pragma unroll
        for (int kt = 0; kt < 4; ++kt)
            afr[nt][kt] = *(const bf16x8*)(wzh + (size_t)co * 128 + kt * 32 + lg * 8);
    }

    const short* Zb = Z + (size_t)b * 16 * 4096 * 8;
    f32x4 o[2][8];
#pragma unroll
    for (int nt = 0; nt < 2; ++nt)
#pragma unroll
        for (int dt = 0; dt < 8; ++dt)
#pragma unroll
            for (int e = 0; e < 4; ++e) o[nt][dt][e] = 0.f;

#pragma unroll
    for (int dt = 0; dt < 8; ++dt) {
        int lpix = l0 + dt * 16 + lr;
#pragma unroll
        for (int kt = 0; kt < 4; ++kt) {
            bf16x8 bz = *(const bf16x8*)(Zb + ((size_t)(kt * 4 + lg) * 4096 + lpix) * 8);
            o[0][dt] = __builtin_amdgcn_mfma_f32_16x16x32_bf16(afr[0][kt], bz, o[0][dt], 0, 0, 0);
            o[1][dt] = __builtin_amdgcn_mfma_f32_16x16x32_bf16(afr[1][kt], bz, o[1][dt], 0, 0, 0);
        }
    }

#pragma unroll
    for (int nt = 0; nt < 2; ++nt)
#pragma unroll
        for (int rr = 0; rr < 4; ++rr) {
            int co = co0 + nt * 16 + lg * 4 + rr;
            float bv = wzb[co];
            const float* xb = x + ((size_t)b * 256 + co) * 4096;
            float* ob = out + ((size_t)b * 256 + co) * 4096;
#pragma unroll
            for (int dt = 0; dt < 8; ++dt) {
                int lpix = l0 + dt * 16 + lr;
                ob[lpix] = o[nt][dt][rr] + bv + xb[lpix];
            }
        }
}

extern "C" void kernel_launch(void* const* d_in, const int* in_sizes, int n_in,
                              void* d_out, int out_size, void* d_ws, size_t ws_size,
                              hipStream_t stream)
{
    const float* x       = (const float*)d_in[0];
    const float* theta_w = (const float*)d_in[1];
    const float* theta_b = (const float*)d_in[2];
    const float* phi_w   = (const float*)d_in[3];
    const float* phi_b   = (const float*)d_in[4];
    const float* g_w     = (const float*)d_in[5];
    const float* g_b     = (const float*)d_in[6];
    const float* wz_w    = (const float*)d_in[7];
    const float* wz_b    = (const float*)d_in[8];
    float* out = (float*)d_out;

    short* ws      = (short*)d_ws;
    short* xT      = ws;                         // [B,4096,256]  8388608
    short* xpT     = xT  + (size_t)8388608;      // [B,1024,256]  2097152
    short* theta_h = xpT + (size_t)2097152;      // [B,4096,128]  4194304
    short* phi_h   = theta_h + (size_t)4194304;  // [B,32,4096]   1048576
    short* G_h     = phi_h + (size_t)1048576;    // [B,32,4096]   1048576
    short* Z       = G_h  + (size_t)1048576;     // [B,16,4096,8] 4194304
    short* wh      = Z    + (size_t)4194304;     // 131072 bf16 weights
    short* th_wh = wh;
    short* ph_wh = wh + 32768;
    short* g_wh  = wh + 65536;
    short* wz_wh = wh + 98304;

    wcvt_k<<<dim3(128), 256, 0, stream>>>(theta_w, phi_w, g_w, wz_w, wh);

    pool_transpose_k<<<dim3(32, 4, BATCH), 256, 0, stream>>>(x, xT, xpT);

    mfma_conv_th_k<<<dim3(64, 2, BATCH), 256, 0, stream>>>(
        xT, th_wh, theta_b, theta_h);

    mfma_conv_pg_k<<<dim3(16, 2, 16), 256, 0, stream>>>(
        xpT, ph_wh, phi_b, g_wh, g_b, phi_h, G_h);

    attn_v6<<<dim3(256), 512, 0, stream>>>(theta_h, phi_h, G_h, Z);

    conv_fin_k<<<dim3(16, 4, BATCH), 256, 0, stream>>>(Z, wz_wh, wz_b, x, out);
}

// Round 7
// 114.392 us; speedup vs baseline: 1.0111x; 1.0111x over previous
//
#include <hip/hip_runtime.h>
#include <math.h>

#define BATCH 8
#define CINCH 256
#define CMID  128
#define NPIX  4096   // 64*64
#define MPIX  1024   // 32*32

typedef __attribute__((ext_vector_type(8))) short bf16x8;
typedef __attribute__((ext_vector_type(4))) short s16x4;
typedef __attribute__((ext_vector_type(4))) float f32x4;

static __device__ __forceinline__ short f2bf(float f) {
    unsigned u = __float_as_uint(f);
    u = (u + 0x7fffu + ((u >> 16) & 1u)) >> 16;   // RNE bf16
    return (short)u;
}

static __device__ __forceinline__ void gl16(const void* g, void* l) {
    __builtin_amdgcn_global_load_lds(
        (const __attribute__((address_space(1))) void*)g,
        (__attribute__((address_space(3))) void*)l, 16, 0, 0);
}

// ---------------------------------------------------------------------------
// prep_k: blocks 0..1023 = pool/transpose; 1024..1151 = weight f32->bf16 cvt.
//   x[B,256,4096] f32 -> xT[B,4096,256] bf16, xpT[B,1024,256] bf16
// ---------------------------------------------------------------------------
__global__ __launch_bounds__(256)
void prep_k(const float* __restrict__ x, short* __restrict__ xT,
            short* __restrict__ xpT,
            const float* __restrict__ wa, const float* __restrict__ wb,
            const float* __restrict__ wc, const float* __restrict__ wd,
            short* __restrict__ wo)
{
    __shared__ float lds[128 * 65];
    const int bid = blockIdx.x;
    const int t   = threadIdx.x;

    if (bid >= 1024) {   // ---- weight convert: 128 blocks
        int i = ((bid - 1024) * 256 + t) * 4;   // 131072 total
        const float* src; int j;
        if (i < 32768)       { src = wa; j = i; }
        else if (i < 65536)  { src = wb; j = i - 32768; }
        else if (i < 98304)  { src = wc; j = i - 65536; }
        else                 { src = wd; j = i - 98304; }
        float4 v = *(const float4*)(src + j);
        s16x4 r = { f2bf(v.x), f2bf(v.y), f2bf(v.z), f2bf(v.w) };
        *(s16x4*)(wo + i) = r;
        return;
    }

    const int r   = bid & 31;         // pooled row hp
    const int cht = (bid >> 5) & 3;   // ch tile
    const int b   = bid >> 7;
    const int wl  = t & 63;
    const int cq  = t >> 6;

    const float* xb = x + ((size_t)b * 256 + cht * 64) * 4096 + r * 128;
#pragma unroll
    for (int hh = 0; hh < 2; ++hh)
#pragma unroll
        for (int i = 0; i < 16; ++i) {
            int ch = cq + i * 4;
            lds[(hh * 64 + wl) * 65 + ch] = xb[(size_t)ch * 4096 + hh * 64 + wl];
        }
    __syncthreads();

    short* xTb = xT + ((size_t)b * 4096 + r * 128) * 256 + cht * 64;
#pragma unroll
    for (int j = 0; j < 32; ++j) {
        int lrow = cq * 32 + j;
        xTb[(size_t)lrow * 256 + wl] = f2bf(lds[lrow * 65 + wl]);
    }
    short* xpb = xpT + ((size_t)b * 1024 + r * 32) * 256 + cht * 64;
#pragma unroll
    for (int k = 0; k < 8; ++k) {
        int wp = cq * 8 + k;
        float v = fmaxf(fmaxf(lds[(2 * wp) * 65 + wl], lds[(2 * wp + 1) * 65 + wl]),
                        fmaxf(lds[(64 + 2 * wp) * 65 + wl], lds[(64 + 2 * wp + 1) * 65 + wl]));
        xpb[(size_t)wp * 256 + wl] = f2bf(v);
    }
}

// ---------------------------------------------------------------------------
// convs_k: blocks 0..1023 = theta conv (16 rows x 64 co per wave);
//          1024..1535 = phi/g conv (frag-order epilogues).
// ---------------------------------------------------------------------------
__global__ __launch_bounds__(256)
void convs_k(const short* __restrict__ xT, const short* __restrict__ xpT,
             const short* __restrict__ th_wh, const float* __restrict__ th_b,
             const short* __restrict__ ph_wh, const float* __restrict__ ph_b,
             const short* __restrict__ g_wh,  const float* __restrict__ g_b,
             short* __restrict__ thetaO, short* __restrict__ phiO,
             short* __restrict__ gO)
{
    const int bid = blockIdx.x;
    const int t  = threadIdx.x;
    const int wv = t >> 6;
    const int l  = t & 63;
    const int lr = l & 15;
    const int lg = l >> 4;

    const short* inT; const short* wb; const float* bias;
    int b, coH, m0, mode;   // mode 0: theta, 1: phi, 2: g
    if (bid < 1024) {
        mode = 0;
        b   = bid >> 7;
        coH = (bid >> 6) & 1;
        m0  = (bid & 63) * 64 + wv * 16;
        inT = xT;  wb = th_wh; bias = th_b;
    } else {
        int idx = bid - 1024;
        int ep  = idx & 16 ? 0 : 0;   // placeholder
        int z   = idx >> 5;
        mode = (z & 1) ? 2 : 1;
        b   = z >> 1;
        coH = (idx >> 4) & 1;
        m0  = (idx & 15) * 64 + wv * 16;
        inT = xpT; wb = (mode == 2) ? g_wh : ph_wh; bias = (mode == 2) ? g_b : ph_b;
        (void)ep;
    }
    wb += (size_t)coH * 64 * 256;

    const size_t inb = ((size_t)b * (mode == 0 ? NPIX : MPIX)) * 256 + lg * 8;

    f32x4 o[4];
#pragma unroll
    for (int dt = 0; dt < 4; ++dt)
#pragma unroll
        for (int e = 0; e < 4; ++e) o[dt][e] = 0.f;

    for (int kt = 0; kt < 8; ++kt) {
        bf16x8 a = *(const bf16x8*)(inT + inb + (size_t)(m0 + lr) * 256 + kt * 32);
#pragma unroll
        for (int dt = 0; dt < 4; ++dt) {
            bf16x8 bv = *(const bf16x8*)(wb + (size_t)(dt * 16 + lr) * 256 + kt * 32 + lg * 8);
            o[dt] = __builtin_amdgcn_mfma_f32_16x16x32_bf16(a, bv, o[dt], 0, 0, 0);
        }
    }

    float bv4[4];
#pragma unroll
    for (int dt = 0; dt < 4; ++dt) bv4[dt] = bias[coH * 64 + dt * 16 + lr];

    if (mode == 0) {        // theta [b][n][128]
        short* ob = thetaO + ((size_t)b * NPIX) * 128;
#pragma unroll
        for (int rr = 0; rr < 4; ++rr) {
            int n = m0 + lg * 4 + rr;
#pragma unroll
            for (int dt = 0; dt < 4; ++dt)
                ob[(size_t)n * 128 + coH * 64 + dt * 16 + lr] = f2bf(o[dt][rr] + bv4[dt]);
        }
    } else if (mode == 1) { // phi frag-order
        short* ob = phiO + (size_t)b * 32 * 4096;
#pragma unroll
        for (int rr = 0; rr < 4; ++rr) {
            int m = m0 + lg * 4 + rr;
            short* cb = ob + (size_t)(m >> 5) * 4096 + ((m >> 4) & 1) * 512 + (m & 15) * 8;
#pragma unroll
            for (int dt = 0; dt < 4; ++dt) {
                int cc = coH * 64 + dt * 16 + lr;
                cb[(cc >> 5) * 1024 + ((cc >> 3) & 3) * 128 + (cc & 7)]
                    = f2bf(o[dt][rr] + bv4[dt]);
            }
        }
    } else {                // G frag-order (ch-major granules)
        short* cb = gO + (size_t)b * 32 * 4096 + (size_t)(m0 >> 5) * 4096;
        const int keyblk = ((m0 >> 4) & 1) * 2 + (lg >> 1);
#pragma unroll
        for (int dt = 0; dt < 4; ++dt) {
            int cc = coH * 64 + dt * 16 + lr;
            s16x4 sv;
#pragma unroll
            for (int rr = 0; rr < 4; ++rr) sv[rr] = f2bf(o[dt][rr] + bv4[dt]);
            *(s16x4*)(cb + (size_t)((cc >> 4) * 64 + keyblk * 16 + (cc & 15)) * 8
                         + (lg & 1) * 4) = sv;
        }
    }
}

// ---------------------------------------------------------------------------
// MFMA attention v7: 4 waves x 32 queries (2 sets/wave) — phi/G LDS reads
// shared across both sets -> ~2x less LDS traffic. Triple-buffered staging,
// counted vmcnt(4). 256 blocks (b -> XCD), 256 threads, 1 block/CU.
// ---------------------------------------------------------------------------
__global__ __launch_bounds__(256, 1)
void attn_v7(const short* __restrict__ theta, const short* __restrict__ phi_sw,
             const short* __restrict__ G_sw, short* __restrict__ Z)
{
    __shared__ short phiL[3][4096];
    __shared__ short gL[3][4096];
    __shared__ short pl4[4][2][512];

    const int t  = threadIdx.x;
    const int wv = t >> 6;
    const int l  = t & 63;
    const int lr = l & 15;
    const int lg = l >> 4;
    const int bid = blockIdx.x;
    const int b   = bid & 7;            // batch -> XCD
    const int s   = bid >> 3;           // 0..31: n & 31

    const short* thb = theta + (size_t)b * NPIX * 128;
    const char*  phC = (const char*)phi_sw + (size_t)b * 32 * 8192;
    const char*  gC  = (const char*)G_sw  + (size_t)b * 32 * 8192;

    auto STAGE = [&](int bufi, int chunk) {
        const char* ps = phC + (size_t)chunk * 8192 + wv * 1024 + l * 16;
        const char* gs = gC  + (size_t)chunk * 8192 + wv * 1024 + l * 16;
        gl16(ps,        (char*)&phiL[bufi][0] + wv * 1024);
        gl16(ps + 4096, (char*)&phiL[bufi][0] + 4096 + wv * 1024);
        gl16(gs,        (char*)&gL[bufi][0] + wv * 1024);
        gl16(gs + 4096, (char*)&gL[bufi][0] + 4096 + wv * 1024);
    };

    STAGE(0, 0);
    STAGE(1, 1);

    // theta B-frags: set u query n = ((wv*2+u)*16 + lr)*32 + s
    bf16x8 bq[2][4];
#pragma unroll
    for (int u = 0; u < 2; ++u) {
        int n = ((wv * 2 + u) * 16 + lr) * 32 + s;
#pragma unroll
        for (int kt = 0; kt < 4; ++kt)
            bq[u][kt] = *(const bf16x8*)(thb + (size_t)n * 128 + kt * 32 + lg * 8);
    }

    f32x4 o[2][8];
#pragma unroll
    for (int u = 0; u < 2; ++u)
#pragma unroll
        for (int dt = 0; dt < 8; ++dt)
#pragma unroll
            for (int e = 0; e < 4; ++e) o[u][dt][e] = 0.f;
    float rm[2] = { -1e30f, -1e30f }, ps_[2] = { 0.f, 0.f };

    for (int c = 0; c < 32; ++c) {
        if (c < 31) asm volatile("s_waitcnt vmcnt(4)" ::: "memory");
        else        asm volatile("s_waitcnt vmcnt(0)" ::: "memory");
        __syncthreads();
        if (c < 30) STAGE((c + 2) % 3, c + 2);

        const int cur = c % 3;
        const char* pb = (const char*)&phiL[cur][0];
        const char* gb = (const char*)&gL[cur][0];

        // ---- QK^T for both sets, shared phi A-frag reads
        f32x4 ssw[2][2];
#pragma unroll
        for (int u = 0; u < 2; ++u)
#pragma unroll
            for (int mt = 0; mt < 2; ++mt)
#pragma unroll
                for (int e = 0; e < 4; ++e) ssw[u][mt][e] = 0.f;
#pragma unroll
        for (int kt = 0; kt < 4; ++kt) {
            bf16x8 a0 = *(const bf16x8*)(pb + ((kt * 2 + 0) * 64 + l) * 16);
            bf16x8 a1 = *(const bf16x8*)(pb + ((kt * 2 + 1) * 64 + l) * 16);
#pragma unroll
            for (int u = 0; u < 2; ++u) {
                ssw[u][0] = __builtin_amdgcn_mfma_f32_16x16x32_bf16(a0, bq[u][kt], ssw[u][0], 0, 0, 0);
                ssw[u][1] = __builtin_amdgcn_mfma_f32_16x16x32_bf16(a1, bq[u][kt], ssw[u][1], 0, 0, 0);
            }
        }

        // ---- G B-frags once, shared by both sets' PV
        bf16x8 gf[8];
#pragma unroll
        for (int dt = 0; dt < 8; ++dt)
            gf[dt] = *(const bf16x8*)(gb + (dt * 64 + l) * 16);

#pragma unroll
        for (int u = 0; u < 2; ++u) {
            // ---- defer-max online softmax (query col = lr)
            float cmx = fmaxf(
                fmaxf(fmaxf(ssw[u][0][0], ssw[u][0][1]), fmaxf(ssw[u][0][2], ssw[u][0][3])),
                fmaxf(fmaxf(ssw[u][1][0], ssw[u][1][1]), fmaxf(ssw[u][1][2], ssw[u][1][3])));
            if (__any(cmx > rm[u] + 8.f)) {
                float cm = cmx;
                cm = fmaxf(cm, __shfl_xor(cm, 16));
                cm = fmaxf(cm, __shfl_xor(cm, 32));
                float nm = fmaxf(rm[u], cm);
                float sc = __expf(rm[u] - nm);
                ps_[u] *= sc;
                rm[u] = nm;
                float scg[4];
#pragma unroll
                for (int rr = 0; rr < 4; ++rr) scg[rr] = __shfl(sc, lg * 4 + rr);
#pragma unroll
                for (int dt = 0; dt < 8; ++dt)
#pragma unroll
                    for (int rr = 0; rr < 4; ++rr) o[u][dt][rr] *= scg[rr];
            }

            // ---- P = exp(S^T - rm): packed 8B stores, conflict-free
#pragma unroll
            for (int mt = 0; mt < 2; ++mt) {
                s16x4 pv;
#pragma unroll
                for (int rr = 0; rr < 4; ++rr) {
                    float p = __expf(ssw[u][mt][rr] - rm[u]);
                    ps_[u] += p;
                    pv[rr] = f2bf(p);
                }
                *(s16x4*)(&pl4[wv][u][0] + ((mt * 2 + (lg >> 1)) * 16 + lr) * 8 + (lg & 1) * 4) = pv;
            }

            // ---- PV
            bf16x8 pa = *(const bf16x8*)(&pl4[wv][u][0] + l * 8);
#pragma unroll
            for (int dt = 0; dt < 8; ++dt)
                o[u][dt] = __builtin_amdgcn_mfma_f32_16x16x32_bf16(pa, gf[dt], o[u][dt], 0, 0, 0);
        }
    }

    // ---- finalize both sets
    short* Zb = Z + (size_t)b * 16 * 4096 * 8;
#pragma unroll
    for (int u = 0; u < 2; ++u) {
        float tot = ps_[u];
        tot += __shfl_xor(tot, 16);
        tot += __shfl_xor(tot, 32);
        float inv = 1.f / tot;
        float invg[4];
#pragma unroll
        for (int rr = 0; rr < 4; ++rr) invg[rr] = __shfl(inv, lg * 4 + rr);
#pragma unroll
        for (int dt = 0; dt < 8; ++dt) {
            s16x4 zv;
#pragma unroll
            for (int rr = 0; rr < 4; ++rr) zv[rr] = f2bf(o[u][dt][rr] * invg[rr]);
            size_t g = (size_t)((wv * 2 + u) * 2 + (lg >> 1)) * 4096 + s * 128 + dt * 16 + lr;
            *(s16x4*)(Zb + g * 8 + (lg & 1) * 4) = zv;
        }
    }
}

// ---------------------------------------------------------------------------
// Final conv: out[b][256 co][4096 l] = wz @ m3 + bias + x. bf16 wz direct.
// ---------------------------------------------------------------------------
__global__ __launch_bounds__(256)
void conv_fin_k(const short* __restrict__ Z, const short* __restrict__ wzh,
                const float* __restrict__ wzb, const float* __restrict__ x,
                float* __restrict__ out)
{
    const int t  = threadIdx.x;
    const int wv = t >> 6;
    const int l  = t & 63;
    const int lr = l & 15;
    const int lg = l >> 4;
    const int b  = blockIdx.z;
    const int co0 = blockIdx.y * 64 + (wv >> 1) * 32;
    const int l0  = blockIdx.x * 256 + (wv & 1) * 128;

    bf16x8 afr[2][4];
#pragma unroll
    for (int nt = 0; nt < 2; ++nt) {
        int co = co0 + nt * 16 + lr;
#pragma unroll
        for (int kt = 0; kt < 4; ++kt)
            afr[nt][kt] = *(const bf16x8*)(wzh + (size_t)co * 128 + kt * 32 + lg * 8);
    }

    const short* Zb = Z + (size_t)b * 16 * 4096 * 8;
    f32x4 o[2][8];
#pragma unroll
    for (int nt = 0; nt < 2; ++nt)
#pragma unroll
        for (int dt = 0; dt < 8; ++dt)
#pragma unroll
            for (int e = 0; e < 4; ++e) o[nt][dt][e] = 0.f;

#pragma unroll
    for (int dt = 0; dt < 8; ++dt) {
        int lpix = l0 + dt * 16 + lr;
#pragma unroll
        for (int kt = 0; kt < 4; ++kt) {
            bf16x8 bz = *(const bf16x8*)(Zb + ((size_t)(kt * 4 + lg) * 4096 + lpix) * 8);
            o[0][dt] = __builtin_amdgcn_mfma_f32_16x16x32_bf16(afr[0][kt], bz, o[0][dt], 0, 0, 0);
            o[1][dt] = __builtin_amdgcn_mfma_f32_16x16x32_bf16(afr[1][kt], bz, o[1][dt], 0, 0, 0);
        }
    }

#pragma unroll
    for (int nt = 0; nt < 2; ++nt)
#pragma unroll
        for (int rr = 0; rr < 4; ++rr) {
            int co = co0 + nt * 16 + lg * 4 + rr;
            float bv = wzb[co];
            const float* xb = x + ((size_t)b * 256 + co) * 4096;
            float* ob = out + ((size_t)b * 256 + co) * 4096;
#pragma unroll
            for (int dt = 0; dt < 8; ++dt) {
                int lpix = l0 + dt * 16 + lr;
                ob[lpix] = o[nt][dt][rr] + bv + xb[lpix];
            }
        }
}

extern "C" void kernel_launch(void* const* d_in, const int* in_sizes, int n_in,
                              void* d_out, int out_size, void* d_ws, size_t ws_size,
                              hipStream_t stream)
{
    const float* x       = (const float*)d_in[0];
    const float* theta_w = (const float*)d_in[1];
    const float* theta_b = (const float*)d_in[2];
    const float* phi_w   = (const float*)d_in[3];
    const float* phi_b   = (const float*)d_in[4];
    const float* g_w     = (const float*)d_in[5];
    const float* g_b     = (const float*)d_in[6];
    const float* wz_w    = (const float*)d_in[7];
    const float* wz_b    = (const float*)d_in[8];
    float* out = (float*)d_out;

    short* ws      = (short*)d_ws;
    short* xT      = ws;                         // [B,4096,256]  8388608
    short* xpT     = xT  + (size_t)8388608;      // [B,1024,256]  2097152
    short* theta_h = xpT + (size_t)2097152;      // [B,4096,128]  4194304
    short* phi_h   = theta_h + (size_t)4194304;  // [B,32,4096]   1048576
    short* G_h     = phi_h + (size_t)1048576;    // [B,32,4096]   1048576
    short* Z       = G_h  + (size_t)1048576;     // [B,16,4096,8] 4194304
    short* wh      = Z    + (size_t)4194304;     // 131072 bf16 weights
    short* th_wh = wh;
    short* ph_wh = wh + 32768;
    short* g_wh  = wh + 65536;
    short* wz_wh = wh + 98304;

    prep_k<<<dim3(1152), 256, 0, stream>>>(x, xT, xpT,
                                           theta_w, phi_w, g_w, wz_w, wh);

    convs_k<<<dim3(1536), 256, 0, stream>>>(xT, xpT,
                                            th_wh, theta_b, ph_wh, phi_b,
                                            g_wh, g_b, theta_h, phi_h, G_h);

    attn_v7<<<dim3(256), 256, 0, stream>>>(theta_h, phi_h, G_h, Z);

    conv_fin_k<<<dim3(16, 4, BATCH), 256, 0, stream>>>(Z, wz_wh, wz_b, x, out);
}

// Round 8
// 98.969 us; speedup vs baseline: 1.1687x; 1.1558x over previous
//
#include <hip/hip_runtime.h>
#include <math.h>

#define BATCH 8
#define CINCH 256
#define CMID  128
#define NPIX  4096   // 64*64
#define MPIX  1024   // 32*32

typedef __attribute__((ext_vector_type(8))) short bf16x8;
typedef __attribute__((ext_vector_type(4))) short s16x4;
typedef __attribute__((ext_vector_type(4))) float f32x4;

static __device__ __forceinline__ short f2bf(float f) {
    unsigned u = __float_as_uint(f);
    u = (u + 0x7fffu + ((u >> 16) & 1u)) >> 16;   // RNE bf16
    return (short)u;
}
static __device__ __forceinline__ float bf2f(short s) {
    return __uint_as_float(((unsigned)(unsigned short)s) << 16);
}

static __device__ __forceinline__ void gl16(const void* g, void* l) {
    __builtin_amdgcn_global_load_lds(
        (const __attribute__((address_space(1))) void*)g,
        (__attribute__((address_space(3))) void*)l, 16, 0, 0);
}

// ---------------------------------------------------------------------------
// Weight f32->bf16 pre-convert. theta_w scaled by log2(e) (softmax in exp2
// domain; softmax is shift/scale-consistent: P=2^(S*log2e-40) normalized).
// ---------------------------------------------------------------------------
__global__ __launch_bounds__(256)
void wcvt_k(const float* __restrict__ a, const float* __restrict__ b,
            const float* __restrict__ c, const float* __restrict__ d,
            short* __restrict__ o)
{
    int i = (blockIdx.x * 256 + threadIdx.x) * 4;   // 131072 total
    const float* src; int j; float sc;
    if (i < 32768)       { src = a; j = i;         sc = 1.44269504f; }
    else if (i < 65536)  { src = b; j = i - 32768; sc = 1.f; }
    else if (i < 98304)  { src = c; j = i - 65536; sc = 1.f; }
    else                 { src = d; j = i - 98304; sc = 1.f; }
    float4 v = *(const float4*)(src + j);
    s16x4 r = { f2bf(v.x * sc), f2bf(v.y * sc), f2bf(v.z * sc), f2bf(v.w * sc) };
    *(s16x4*)(o + i) = r;
}

// ---------------------------------------------------------------------------
// front_k: fused transpose + theta conv + maxpool + phi/g convs.
// Block (b = bid&7 -> XCD, r = bid>>3): covers l = r*128..+127 (h rows 2r,2r+1)
// = pooled chunk r (keys r*32..+31). One x read; outputs in attn-native
// layouts: theta [b][n][128], phi/G frag-order chunks.
// ---------------------------------------------------------------------------
__global__ __launch_bounds__(512)
void front_k(const float* __restrict__ x,
             const short* __restrict__ th_wh, const float* __restrict__ th_b,
             const short* __restrict__ ph_wh, const float* __restrict__ ph_b,
             const short* __restrict__ g_wh,  const float* __restrict__ g_b,
             short* __restrict__ thetaO, short* __restrict__ phiO,
             short* __restrict__ gO)
{
    __shared__ float F[128 * 65];     // f32 transpose tile (per 64-ch slice)
    __shared__ short X[128 * 264];    // bf16 [l 128][ch 256] (+8 pad)
    __shared__ short P[32 * 264];     // pooled bf16 [wp 32][ch 256]

    const int bid = blockIdx.x;
    const int t   = threadIdx.x;
    const int b   = bid & 7;
    const int r   = bid >> 3;
    const int wv  = t >> 6;
    const int l   = t & 63;
    const int lr  = l & 15;
    const int lg  = l >> 4;

    // ---- Phase A: x -> bf16 transposed tile (4 ch-slices)
    const int hh = wv & 1;      // h-row within pair
    const int c0 = t >> 7;      // 0..3
    for (int ct = 0; ct < 4; ++ct) {
        const float* xb = x + ((size_t)(b * 256 + ct * 64)) * 4096 + r * 128;
#pragma unroll
        for (int i = 0; i < 16; ++i) {
            int ch = c0 + i * 4;
            F[(hh * 64 + l) * 65 + ch] = xb[(size_t)ch * 4096 + hh * 64 + l];
        }
        __syncthreads();
#pragma unroll
        for (int i = 0; i < 16; ++i) {
            int row = wv + i * 8;
            X[row * 264 + ct * 64 + l] = f2bf(F[row * 65 + l]);
        }
        __syncthreads();
    }

    // ---- Phase B: maxpool into P (bf16 max = bit-exact)
#pragma unroll
    for (int i = 0; i < 4; ++i) {
        int slot = i * 512 + t;
        int wp = slot >> 6, c4 = slot & 63;
        s16x4 v0 = *(const s16x4*)(X + (2 * wp) * 264 + c4 * 4);
        s16x4 v1 = *(const s16x4*)(X + (2 * wp + 1) * 264 + c4 * 4);
        s16x4 v2 = *(const s16x4*)(X + (64 + 2 * wp) * 264 + c4 * 4);
        s16x4 v3 = *(const s16x4*)(X + (65 + 2 * wp) * 264 + c4 * 4);
        s16x4 rm;
#pragma unroll
        for (int e = 0; e < 4; ++e) {
            float m = fmaxf(fmaxf(bf2f(v0[e]), bf2f(v1[e])),
                            fmaxf(bf2f(v2[e]), bf2f(v3[e])));
            rm[e] = f2bf(m);
        }
        *(s16x4*)(P + wp * 264 + c4 * 4) = rm;
    }
    __syncthreads();

    // ---- Phase C1: theta conv (all 8 waves, 16 rows x 128 co each)
    {
        const int m0 = wv * 16;
        f32x4 o[8];
#pragma unroll
        for (int dt = 0; dt < 8; ++dt)
#pragma unroll
            for (int e = 0; e < 4; ++e) o[dt][e] = 0.f;
        for (int kt = 0; kt < 8; ++kt) {
            bf16x8 a = *(const bf16x8*)(X + (m0 + lr) * 264 + kt * 32 + lg * 8);
#pragma unroll
            for (int dt = 0; dt < 8; ++dt) {
                bf16x8 bv = *(const bf16x8*)(th_wh + (size_t)(dt * 16 + lr) * 256 + kt * 32 + lg * 8);
                o[dt] = __builtin_amdgcn_mfma_f32_16x16x32_bf16(a, bv, o[dt], 0, 0, 0);
            }
        }
        float bvt[8];
#pragma unroll
        for (int dt = 0; dt < 8; ++dt) bvt[dt] = th_b[dt * 16 + lr] * 1.44269504f;
        short* ob = thetaO + (size_t)b * NPIX * 128;
#pragma unroll
        for (int rr = 0; rr < 4; ++rr) {
            int n = r * 128 + m0 + lg * 4 + rr;
#pragma unroll
            for (int dt = 0; dt < 8; ++dt)
                ob[(size_t)n * 128 + dt * 16 + lr] = f2bf(o[dt][rr] + bvt[dt]);
        }
    }

    // ---- Phase C2: phi (waves 0-3) / G (waves 4-7): 16 rows x 64 co each
    {
        const int half = wv & 1;
        const int coH  = (wv >> 1) & 1;
        const short* wsel = ((wv < 4) ? ph_wh : g_wh) + (size_t)coH * 64 * 256;
        const float* bsel = (wv < 4) ? ph_b : g_b;

        f32x4 q[4];
#pragma unroll
        for (int dt = 0; dt < 4; ++dt)
#pragma unroll
            for (int e = 0; e < 4; ++e) q[dt][e] = 0.f;
        for (int kt = 0; kt < 8; ++kt) {
            bf16x8 a = *(const bf16x8*)(P + (half * 16 + lr) * 264 + kt * 32 + lg * 8);
#pragma unroll
            for (int dt = 0; dt < 4; ++dt) {
                bf16x8 bv = *(const bf16x8*)(wsel + (size_t)(dt * 16 + lr) * 256 + kt * 32 + lg * 8);
                q[dt] = __builtin_amdgcn_mfma_f32_16x16x32_bf16(a, bv, q[dt], 0, 0, 0);
            }
        }
        float bv4[4];
#pragma unroll
        for (int dt = 0; dt < 4; ++dt) bv4[dt] = bsel[coH * 64 + dt * 16 + lr];

        if (wv < 4) {   // phi frag-order
            short* cb = phiO + (size_t)b * 32 * 4096 + (size_t)r * 4096;
#pragma unroll
            for (int rr = 0; rr < 4; ++rr) {
                int mloc = half * 16 + lg * 4 + rr;
                short* cbb = cb + (mloc >> 4) * 512 + (mloc & 15) * 8;
#pragma unroll
                for (int dt = 0; dt < 4; ++dt) {
                    int cc = coH * 64 + dt * 16 + lr;
                    cbb[(cc >> 5) * 1024 + ((cc >> 3) & 3) * 128 + (cc & 7)]
                        = f2bf(q[dt][rr] + bv4[dt]);
                }
            }
        } else {        // G frag-order (ch-major granules)
            short* cb = gO + (size_t)b * 32 * 4096 + (size_t)r * 4096;
            const int keyblk = half * 2 + (lg >> 1);
#pragma unroll
            for (int dt = 0; dt < 4; ++dt) {
                int cc = coH * 64 + dt * 16 + lr;
                s16x4 sv;
#pragma unroll
                for (int rr = 0; rr < 4; ++rr) sv[rr] = f2bf(q[dt][rr] + bv4[dt]);
                *(s16x4*)(cb + (size_t)((cc >> 4) * 64 + keyblk * 16 + (cc & 15)) * 8
                             + (lg & 1) * 4) = sv;
            }
        }
    }
}

// ---------------------------------------------------------------------------
// attn_v8: key-split-2. 8 waves: group g = wv>>2 handles chunks g*16..+15,
// each wave 32 queries (2 sets). Fixed-shift softmax P = 2^(S2 - 40) (theta
// pre-scaled by log2e) -> no max tracking; partials merged by plain SUM.
// Triple-buffered staging per group, counted vmcnt(4).
// ---------------------------------------------------------------------------
__global__ __launch_bounds__(512)
void attn_v8(const short* __restrict__ theta, const short* __restrict__ phi_sw,
             const short* __restrict__ G_sw, short* __restrict__ Z)
{
    __shared__ __align__(16) char smem[114688];  // 96KB stage + 16KB P slabs
    const int t   = threadIdx.x;
    const int wv  = t >> 6;
    const int l   = t & 63;
    const int lr  = l & 15;
    const int lg  = l >> 4;
    const int gid = wv >> 2;       // key-group
    const int wvl = wv & 3;        // wave-in-group (query identity)
    const int bid = blockIdx.x;
    const int b   = bid & 7;       // batch -> XCD
    const int s   = bid >> 3;      // n & 31

    const short* thb = theta + (size_t)b * NPIX * 128;
    const char*  phC = (const char*)phi_sw + (size_t)b * 32 * 8192;
    const char*  gC  = (const char*)G_sw  + (size_t)b * 32 * 8192;
    const int first = gid * 16;

    auto STAGE = [&](int bufi, int cc) {
        int chunk = first + cc;
        const char* ps = phC + (size_t)chunk * 8192 + wvl * 2048 + l * 16;
        const char* gs = gC  + (size_t)chunk * 8192 + wvl * 2048 + l * 16;
        char* base = smem + (gid * 3 + bufi) * 16384;
        gl16(ps,        base + wvl * 2048);
        gl16(ps + 1024, base + wvl * 2048 + 1024);
        gl16(gs,        base + 8192 + wvl * 2048);
        gl16(gs + 1024, base + 8192 + wvl * 2048 + 1024);
    };

    STAGE(0, 0);
    STAGE(1, 1);

    // theta B-frags: set u query n = ((wvl*2+u)*16 + lr)*32 + s
    bf16x8 bq[2][4];
#pragma unroll
    for (int u = 0; u < 2; ++u) {
        int n = ((wvl * 2 + u) * 16 + lr) * 32 + s;
#pragma unroll
        for (int kt = 0; kt < 4; ++kt)
            bq[u][kt] = *(const bf16x8*)(thb + (size_t)n * 128 + kt * 32 + lg * 8);
    }

    f32x4 o[2][8];
#pragma unroll
    for (int u = 0; u < 2; ++u)
#pragma unroll
        for (int dt = 0; dt < 8; ++dt)
#pragma unroll
            for (int e = 0; e < 4; ++e) o[u][dt][e] = 0.f;
    float ps_[2] = { 0.f, 0.f };

    for (int cc = 0; cc < 16; ++cc) {
        if (cc < 15) asm volatile("s_waitcnt vmcnt(4)" ::: "memory");
        else         asm volatile("s_waitcnt vmcnt(0)" ::: "memory");
        __syncthreads();
        if (cc < 14) STAGE((cc + 2) % 3, cc + 2);

        const short* pb = (const short*)(smem + (gid * 3 + cc % 3) * 16384);
        const short* gb = pb + 4096;

        // ---- S^T = mfma(A=phi, B=theta): D[key][query col=lr]
        f32x4 ssw[2][2];
#pragma unroll
        for (int u = 0; u < 2; ++u)
#pragma unroll
            for (int mt = 0; mt < 2; ++mt)
#pragma unroll
                for (int e = 0; e < 4; ++e) ssw[u][mt][e] = 0.f;
#pragma unroll
        for (int kt = 0; kt < 4; ++kt) {
            bf16x8 a0 = *(const bf16x8*)(pb + ((kt * 2 + 0) * 64 + l) * 8);
            bf16x8 a1 = *(const bf16x8*)(pb + ((kt * 2 + 1) * 64 + l) * 8);
#pragma unroll
            for (int u = 0; u < 2; ++u) {
                ssw[u][0] = __builtin_amdgcn_mfma_f32_16x16x32_bf16(a0, bq[u][kt], ssw[u][0], 0, 0, 0);
                ssw[u][1] = __builtin_amdgcn_mfma_f32_16x16x32_bf16(a1, bq[u][kt], ssw[u][1], 0, 0, 0);
            }
        }

        bf16x8 gf[8];
#pragma unroll
        for (int dt = 0; dt < 8; ++dt)
            gf[dt] = *(const bf16x8*)(gb + (dt * 64 + l) * 8);

#pragma unroll
        for (int u = 0; u < 2; ++u) {
            short* pu = (short*)(smem + 98304 + wv * 2048 + u * 1024);
            // P = 2^(S2 - 40): no max tracking needed
#pragma unroll
            for (int mt = 0; mt < 2; ++mt) {
                s16x4 pv;
#pragma unroll
                for (int rr = 0; rr < 4; ++rr) {
                    float p = exp2f(ssw[u][mt][rr] - 40.f);
                    ps_[u] += p;
                    pv[rr] = f2bf(p);
                }
                *(s16x4*)(pu + ((mt * 2 + (lg >> 1)) * 16 + lr) * 8 + (lg & 1) * 4) = pv;
            }
            bf16x8 pa = *(const bf16x8*)(pu + l * 8);
#pragma unroll
            for (int dt = 0; dt < 8; ++dt)
                o[u][dt] = __builtin_amdgcn_mfma_f32_16x16x32_bf16(pa, gf[dt], o[u][dt], 0, 0, 0);
        }
    }

    // ---- merge partials: upper waves write (o, ps) to LDS; lower waves add
    __syncthreads();
    float* mg = (float*)smem;
    if (wv >= 4) {
        float* mb = mg + (size_t)((wv - 4) * 64 + l) * 68;
#pragma unroll
        for (int u = 0; u < 2; ++u)
#pragma unroll
            for (int dt = 0; dt < 8; ++dt)
                *(f32x4*)(mb + (u * 8 + dt) * 4) = o[u][dt];
        mb[64] = ps_[0]; mb[65] = ps_[1];
    }
    __syncthreads();
    if (wv < 4) {
        const float* mb = mg + (size_t)(wv * 64 + l) * 68;
#pragma unroll
        for (int u = 0; u < 2; ++u)
#pragma unroll
            for (int dt = 0; dt < 8; ++dt) {
                f32x4 pv = *(const f32x4*)(mb + (u * 8 + dt) * 4);
#pragma unroll
                for (int e = 0; e < 4; ++e) o[u][dt][e] += pv[e];
            }
        ps_[0] += mb[64]; ps_[1] += mb[65];

        short* Zb = Z + (size_t)b * 16 * 4096 * 8;
#pragma unroll
        for (int u = 0; u < 2; ++u) {
            float tot = ps_[u];
            tot += __shfl_xor(tot, 16);
            tot += __shfl_xor(tot, 32);
            float inv = 1.f / tot;
            float invg[4];
#pragma unroll
            for (int rr = 0; rr < 4; ++rr) invg[rr] = __shfl(inv, lg * 4 + rr);
            const int wq = wvl * 2 + u;
#pragma unroll
            for (int dt = 0; dt < 8; ++dt) {
                s16x4 zv;
#pragma unroll
                for (int rr = 0; rr < 4; ++rr) zv[rr] = f2bf(o[u][dt][rr] * invg[rr]);
                size_t g = (size_t)(wq * 2 + (lg >> 1)) * 4096 + s * 128 + dt * 16 + lr;
                *(s16x4*)(Zb + g * 8 + (lg & 1) * 4) = zv;
            }
        }
    }
}

// ---------------------------------------------------------------------------
// Final conv: out[b][256 co][4096 l] = wz @ m3 + bias + x. bf16 wz direct.
// ---------------------------------------------------------------------------
__global__ __launch_bounds__(256)
void conv_fin_k(const short* __restrict__ Z, const short* __restrict__ wzh,
                const float* __restrict__ wzb, const float* __restrict__ x,
                float* __restrict__ out)
{
    const int t  = threadIdx.x;
    const int wv = t >> 6;
    const int l  = t & 63;
    const int lr = l & 15;
    const int lg = l >> 4;
    const int b  = blockIdx.z;
    const int co0 = blockIdx.y * 64 + (wv >> 1) * 32;
    const int l0  = blockIdx.x * 256 + (wv & 1) * 128;

    bf16x8 afr[2][4];
#pragma unroll
    for (int nt = 0; nt < 2; ++nt) {
        int co = co0 + nt * 16 + lr;
#pragma unroll
        for (int kt = 0; kt < 4; ++kt)
            afr[nt][kt] = *(const bf16x8*)(wzh + (size_t)co * 128 + kt * 32 + lg * 8);
    }

    const short* Zb = Z + (size_t)b * 16 * 4096 * 8;
    f32x4 o[2][8];
#pragma unroll
    for (int nt = 0; nt < 2; ++nt)
#pragma unroll
        for (int dt = 0; dt < 8; ++dt)
#pragma unroll
            for (int e = 0; e < 4; ++e) o[nt][dt][e] = 0.f;

#pragma unroll
    for (int dt = 0; dt < 8; ++dt) {
        int lpix = l0 + dt * 16 + lr;
#pragma unroll
        for (int kt = 0; kt < 4; ++kt) {
            bf16x8 bz = *(const bf16x8*)(Zb + ((size_t)(kt * 4 + lg) * 4096 + lpix) * 8);
            o[0][dt] = __builtin_amdgcn_mfma_f32_16x16x32_bf16(afr[0][kt], bz, o[0][dt], 0, 0, 0);
            o[1][dt] = __builtin_amdgcn_mfma_f32_16x16x32_bf16(afr[1][kt], bz, o[1][dt], 0, 0, 0);
        }
    }

#pragma unroll
    for (int nt = 0; nt < 2; ++nt)
#pragma unroll
        for (int rr = 0; rr < 4; ++rr) {
            int co = co0 + nt * 16 + lg * 4 + rr;
            float bv = wzb[co];
            const float* xb = x + ((size_t)b * 256 + co) * 4096;
            float* ob = out + ((size_t)b * 256 + co) * 4096;
#pragma unroll
            for (int dt = 0; dt < 8; ++dt) {
                int lpix = l0 + dt * 16 + lr;
                ob[lpix] = o[nt][dt][rr] + bv + xb[lpix];
            }
        }
}

extern "C" void kernel_launch(void* const* d_in, const int* in_sizes, int n_in,
                              void* d_out, int out_size, void* d_ws, size_t ws_size,
                              hipStream_t stream)
{
    const float* x       = (const float*)d_in[0];
    const float* theta_w = (const float*)d_in[1];
    const float* theta_b = (const float*)d_in[2];
    const float* phi_w   = (const float*)d_in[3];
    const float* phi_b   = (const float*)d_in[4];
    const float* g_w     = (const float*)d_in[5];
    const float* g_b     = (const float*)d_in[6];
    const float* wz_w    = (const float*)d_in[7];
    const float* wz_b    = (const float*)d_in[8];
    float* out = (float*)d_out;

    short* ws      = (short*)d_ws;
    short* theta_h = ws;                         // [B,4096,128]  4194304
    short* phi_h   = theta_h + (size_t)4194304;  // [B,32,4096]   1048576
    short* G_h     = phi_h + (size_t)1048576;    // [B,32,4096]   1048576
    short* Z       = G_h  + (size_t)1048576;     // [B,16,4096,8] 4194304
    short* wh      = Z    + (size_t)4194304;     // 131072 bf16 weights
    short* th_wh = wh;
    short* ph_wh = wh + 32768;
    short* g_wh  = wh + 65536;
    short* wz_wh = wh + 98304;

    wcvt_k<<<dim3(128), 256, 0, stream>>>(theta_w, phi_w, g_w, wz_w, wh);

    front_k<<<dim3(256), 512, 0, stream>>>(x, th_wh, theta_b, ph_wh, phi_b,
                                           g_wh, g_b, theta_h, phi_h, G_h);

    attn_v8<<<dim3(256), 512, 0, stream>>>(theta_h, phi_h, G_h, Z);

    conv_fin_k<<<dim3(16, 4, BATCH), 256, 0, stream>>>(Z, wz_wh, wz_b, x, out);
}

// Round 10
// 97.629 us; speedup vs baseline: 1.1847x; 1.0137x over previous
//
#include <hip/hip_runtime.h>
#include <math.h>

#define BATCH 8
#define CINCH 256
#define CMID  128
#define NPIX  4096   // 64*64
#define MPIX  1024   // 32*32

typedef __attribute__((ext_vector_type(8))) short bf16x8;
typedef __attribute__((ext_vector_type(4))) short s16x4;
typedef __attribute__((ext_vector_type(4))) float f32x4;

static __device__ __forceinline__ short f2bf(float f) {
    unsigned u = __float_as_uint(f);
    u = (u + 0x7fffu + ((u >> 16) & 1u)) >> 16;   // RNE bf16
    return (short)u;
}
static __device__ __forceinline__ float bf2f(short s) {
    return __uint_as_float(((unsigned)(unsigned short)s) << 16);
}

static __device__ __forceinline__ void gl16(const void* g, void* l) {
    __builtin_amdgcn_global_load_lds(
        (const __attribute__((address_space(1))) void*)g,
        (__attribute__((address_space(3))) void*)l, 16, 0, 0);
}

// ---------------------------------------------------------------------------
// Weight f32->bf16 pre-convert.
// theta: rows PERMUTED (dest row R holds src row perm(R)=(R&15)*8+(R>>4)),
//        scaled by log2(e). Net effect: theta_h output comes out channel-
//        LINEAR with packed stores (perm cancels in the epilogue).
// phi, g, wz: LINEAR (phi must match linear theta on the QK k-axis!).
// ---------------------------------------------------------------------------
__global__ __launch_bounds__(256)
void wcvt_k(const float* __restrict__ a, const float* __restrict__ b,
            const float* __restrict__ c, const float* __restrict__ d,
            short* __restrict__ o)
{
    int i = (blockIdx.x * 256 + threadIdx.x) * 4;   // 131072 total
    if (i < 32768) {   // theta: permuted rows + log2e scale
        int cr = i >> 8, col = i & 255;
        int R = (cr & 7) * 16 + (cr >> 3);   // perm(R) = cr
        float4 v = *(const float4*)(a + i);
        s16x4 rv = { f2bf(v.x * 1.44269504f), f2bf(v.y * 1.44269504f),
                     f2bf(v.z * 1.44269504f), f2bf(v.w * 1.44269504f) };
        *(s16x4*)(o + R * 256 + col) = rv;
    } else {
        const float* src; int j;
        if (i < 65536)      { src = b; j = i - 32768; }
        else if (i < 98304) { src = c; j = i - 65536; }
        else                { src = d; j = i - 98304; }
        float4 v = *(const float4*)(src + j);
        s16x4 rv = { f2bf(v.x), f2bf(v.y), f2bf(v.z), f2bf(v.w) };
        *(s16x4*)(o + i) = rv;
    }
}

// ---------------------------------------------------------------------------
// front_k: fused transpose + theta conv + maxpool + phi/g convs.
// Phase A: reg-prefetch pipelined x->LDS transpose, lgkm-only barriers.
// theta output channels permuted-weights -> channel-linear packed stores.
// ---------------------------------------------------------------------------
__global__ __launch_bounds__(512)
void front_k(const float* __restrict__ x,
             const short* __restrict__ th_wh, const float* __restrict__ th_b,
             const short* __restrict__ ph_wh, const float* __restrict__ ph_b,
             const short* __restrict__ g_wh,  const float* __restrict__ g_b,
             short* __restrict__ thetaO, short* __restrict__ phiO,
             short* __restrict__ gO)
{
    __shared__ float F[128 * 65];     // f32 transpose tile (per 64-ch slice)
    __shared__ short X[128 * 264];    // bf16 [l 128][ch 256] (+8 pad)
    __shared__ short P[32 * 264];     // pooled bf16 [wp 32][ch 256]

    const int bid = blockIdx.x;
    const int t   = threadIdx.x;
    const int b   = bid & 7;
    const int r   = bid >> 3;
    const int wv  = t >> 6;
    const int l   = t & 63;
    const int lr  = l & 15;
    const int lg  = l >> 4;

    // ---- Phase A: x -> bf16 transposed tile, software-pipelined
    const int hh = wv & 1;
    const int c0 = t >> 7;      // 0..3
    float ra[16], rb[16];
    {
        const float* xb = x + ((size_t)(b * 256)) * 4096 + r * 128;
#pragma unroll
        for (int i = 0; i < 16; ++i)
            ra[i] = xb[(size_t)(c0 + i * 4) * 4096 + hh * 64 + l];
    }
#pragma unroll
    for (int ct = 0; ct < 4; ++ct) {
        if ((ct & 1) == 0) {
#pragma unroll
            for (int i = 0; i < 16; ++i) F[(hh * 64 + l) * 65 + c0 + i * 4] = ra[i];
            if (ct < 3) {
                const float* xb = x + ((size_t)(b * 256 + (ct + 1) * 64)) * 4096 + r * 128;
#pragma unroll
                for (int i = 0; i < 16; ++i)
                    rb[i] = xb[(size_t)(c0 + i * 4) * 4096 + hh * 64 + l];
            }
        } else {
#pragma unroll
            for (int i = 0; i < 16; ++i) F[(hh * 64 + l) * 65 + c0 + i * 4] = rb[i];
            if (ct < 3) {
                const float* xb = x + ((size_t)(b * 256 + (ct + 1) * 64)) * 4096 + r * 128;
#pragma unroll
                for (int i = 0; i < 16; ++i)
                    ra[i] = xb[(size_t)(c0 + i * 4) * 4096 + hh * 64 + l];
            }
        }
        asm volatile("s_waitcnt lgkmcnt(0)" ::: "memory");
        __builtin_amdgcn_s_barrier();
#pragma unroll
        for (int i = 0; i < 16; ++i) {
            int row = wv + i * 8;
            X[row * 264 + ct * 64 + l] = f2bf(F[row * 65 + l]);
        }
        asm volatile("s_waitcnt lgkmcnt(0)" ::: "memory");
        __builtin_amdgcn_s_barrier();
    }

    // ---- Phase B: maxpool into P
#pragma unroll
    for (int i = 0; i < 4; ++i) {
        int slot = i * 512 + t;
        int wp = slot >> 6, c4 = slot & 63;
        s16x4 v0 = *(const s16x4*)(X + (2 * wp) * 264 + c4 * 4);
        s16x4 v1 = *(const s16x4*)(X + (2 * wp + 1) * 264 + c4 * 4);
        s16x4 v2 = *(const s16x4*)(X + (64 + 2 * wp) * 264 + c4 * 4);
        s16x4 v3 = *(const s16x4*)(X + (65 + 2 * wp) * 264 + c4 * 4);
        s16x4 rm;
#pragma unroll
        for (int e = 0; e < 4; ++e) {
            float m = fmaxf(fmaxf(bf2f(v0[e]), bf2f(v1[e])),
                            fmaxf(bf2f(v2[e]), bf2f(v3[e])));
            rm[e] = f2bf(m);
        }
        *(s16x4*)(P + wp * 264 + c4 * 4) = rm;
    }
    __syncthreads();

    // ---- Phase C1: theta conv (permuted weights) -> packed bf16x8 stores
    {
        const int m0 = wv * 16;
        f32x4 o[8];
#pragma unroll
        for (int dt = 0; dt < 8; ++dt)
#pragma unroll
            for (int e = 0; e < 4; ++e) o[dt][e] = 0.f;
        for (int kt = 0; kt < 8; ++kt) {
            bf16x8 a = *(const bf16x8*)(X + (m0 + lr) * 264 + kt * 32 + lg * 8);
#pragma unroll
            for (int dt = 0; dt < 8; ++dt) {
                bf16x8 bv = *(const bf16x8*)(th_wh + (size_t)(dt * 16 + lr) * 256 + kt * 32 + lg * 8);
                o[dt] = __builtin_amdgcn_mfma_f32_16x16x32_bf16(a, bv, o[dt], 0, 0, 0);
            }
        }
        float bvt[8];
#pragma unroll
        for (int dt = 0; dt < 8; ++dt) bvt[dt] = th_b[lr * 8 + dt] * 1.44269504f;
        short* ob = thetaO + (size_t)b * NPIX * 128;
#pragma unroll
        for (int rr = 0; rr < 4; ++rr) {
            int n = r * 128 + m0 + lg * 4 + rr;
            bf16x8 sv;
#pragma unroll
            for (int dt = 0; dt < 8; ++dt) sv[dt] = f2bf(o[dt][rr] + bvt[dt]);
            *(bf16x8*)(ob + (size_t)n * 128 + lr * 8) = sv;
        }
    }

    // ---- Phase C2: phi (waves 0-3, LINEAR weights) / G (waves 4-7)
    {
        const int half = wv & 1;
        const int coH  = (wv >> 1) & 1;
        const short* wsel = ((wv < 4) ? ph_wh : g_wh) + (size_t)coH * 64 * 256;
        const float* bsel = (wv < 4) ? ph_b : g_b;

        f32x4 q[4];
#pragma unroll
        for (int dt = 0; dt < 4; ++dt)
#pragma unroll
            for (int e = 0; e < 4; ++e) q[dt][e] = 0.f;
        for (int kt = 0; kt < 8; ++kt) {
            bf16x8 a = *(const bf16x8*)(P + (half * 16 + lr) * 264 + kt * 32 + lg * 8);
#pragma unroll
            for (int dt = 0; dt < 4; ++dt) {
                bf16x8 bv = *(const bf16x8*)(wsel + (size_t)(dt * 16 + lr) * 256 + kt * 32 + lg * 8);
                q[dt] = __builtin_amdgcn_mfma_f32_16x16x32_bf16(a, bv, q[dt], 0, 0, 0);
            }
        }
        float bv4[4];
#pragma unroll
        for (int dt = 0; dt < 4; ++dt) bv4[dt] = bsel[coH * 64 + dt * 16 + lr];

        if (wv < 4) {   // phi frag-order (k-position = channel, linear)
            short* cb = phiO + (size_t)b * 32 * 4096 + (size_t)r * 4096;
#pragma unroll
            for (int rr = 0; rr < 4; ++rr) {
                int mloc = half * 16 + lg * 4 + rr;
                short* cbb = cb + (mloc >> 4) * 512 + (mloc & 15) * 8;
#pragma unroll
                for (int dt = 0; dt < 4; ++dt) {
                    int cc = coH * 64 + dt * 16 + lr;
                    cbb[(cc >> 5) * 1024 + ((cc >> 3) & 3) * 128 + (cc & 7)]
                        = f2bf(q[dt][rr] + bv4[dt]);
                }
            }
        } else {        // G frag-order (ch-major granules)
            short* cb = gO + (size_t)b * 32 * 4096 + (size_t)r * 4096;
            const int keyblk = half * 2 + (lg >> 1);
#pragma unroll
            for (int dt = 0; dt < 4; ++dt) {
                int cc = coH * 64 + dt * 16 + lr;
                s16x4 sv;
#pragma unroll
                for (int rr = 0; rr < 4; ++rr) sv[rr] = f2bf(q[dt][rr] + bv4[dt]);
                *(s16x4*)(cb + (size_t)((cc >> 4) * 64 + keyblk * 16 + (cc & 15)) * 8
                             + (lg & 1) * 4) = sv;
            }
        }
    }
}

// ---------------------------------------------------------------------------
// attn_v9: key-split-2, fixed-shift exp2 softmax, RAW s_barrier + counted
// vmcnt(4) (loads genuinely span iterations now).
// ---------------------------------------------------------------------------
__global__ __launch_bounds__(512)
void attn_v9(const short* __restrict__ theta, const short* __restrict__ phi_sw,
             const short* __restrict__ G_sw, short* __restrict__ Z)
{
    __shared__ __align__(16) char smem[114688];  // 96KB stage + 16KB P slabs
    const int t   = threadIdx.x;
    const int wv  = t >> 6;
    const int l   = t & 63;
    const int lr  = l & 15;
    const int lg  = l >> 4;
    const int gid = wv >> 2;       // key-group
    const int wvl = wv & 3;        // wave-in-group
    const int bid = blockIdx.x;
    const int b   = bid & 7;       // batch -> XCD
    const int s   = bid >> 3;      // n & 31

    const short* thb = theta + (size_t)b * NPIX * 128;
    const char*  phC = (const char*)phi_sw + (size_t)b * 32 * 8192;
    const char*  gC  = (const char*)G_sw  + (size_t)b * 32 * 8192;
    const int first = gid * 16;

    auto STAGE = [&](int bufi, int cc) {
        int chunk = first + cc;
        const char* ps = phC + (size_t)chunk * 8192 + wvl * 2048 + l * 16;
        const char* gs = gC  + (size_t)chunk * 8192 + wvl * 2048 + l * 16;
        char* base = smem + (gid * 3 + bufi) * 16384;
        gl16(ps,        base + wvl * 2048);
        gl16(ps + 1024, base + wvl * 2048 + 1024);
        gl16(gs,        base + 8192 + wvl * 2048);
        gl16(gs + 1024, base + 8192 + wvl * 2048 + 1024);
    };

    STAGE(0, 0);
    STAGE(1, 1);

    // theta B-frags: set u query n = ((wvl*2+u)*16 + lr)*32 + s
    bf16x8 bq[2][4];
#pragma unroll
    for (int u = 0; u < 2; ++u) {
        int n = ((wvl * 2 + u) * 16 + lr) * 32 + s;
#pragma unroll
        for (int kt = 0; kt < 4; ++kt)
            bq[u][kt] = *(const bf16x8*)(thb + (size_t)n * 128 + kt * 32 + lg * 8);
    }

    f32x4 o[2][8];
#pragma unroll
    for (int u = 0; u < 2; ++u)
#pragma unroll
        for (int dt = 0; dt < 8; ++dt)
#pragma unroll
            for (int e = 0; e < 4; ++e) o[u][dt][e] = 0.f;
    float ps_[2] = { 0.f, 0.f };

    for (int cc = 0; cc < 16; ++cc) {
        if (cc < 15) asm volatile("s_waitcnt vmcnt(4)" ::: "memory");
        else         asm volatile("s_waitcnt vmcnt(0)" ::: "memory");
        __builtin_amdgcn_s_barrier();        // raw: no vmcnt(0) drain
        if (cc < 14) STAGE((cc + 2) % 3, cc + 2);

        const short* pb = (const short*)(smem + (gid * 3 + cc % 3) * 16384);
        const short* gb = pb + 4096;

        // ---- S^T = mfma(A=phi, B=theta): D[key][query col=lr]
        f32x4 ssw[2][2];
#pragma unroll
        for (int u = 0; u < 2; ++u)
#pragma unroll
            for (int mt = 0; mt < 2; ++mt)
#pragma unroll
                for (int e = 0; e < 4; ++e) ssw[u][mt][e] = 0.f;
#pragma unroll
        for (int kt = 0; kt < 4; ++kt) {
            bf16x8 a0 = *(const bf16x8*)(pb + ((kt * 2 + 0) * 64 + l) * 8);
            bf16x8 a1 = *(const bf16x8*)(pb + ((kt * 2 + 1) * 64 + l) * 8);
#pragma unroll
            for (int u = 0; u < 2; ++u) {
                ssw[u][0] = __builtin_amdgcn_mfma_f32_16x16x32_bf16(a0, bq[u][kt], ssw[u][0], 0, 0, 0);
                ssw[u][1] = __builtin_amdgcn_mfma_f32_16x16x32_bf16(a1, bq[u][kt], ssw[u][1], 0, 0, 0);
            }
        }

        bf16x8 gf[8];
#pragma unroll
        for (int dt = 0; dt < 8; ++dt)
            gf[dt] = *(const bf16x8*)(gb + (dt * 64 + l) * 8);

#pragma unroll
        for (int u = 0; u < 2; ++u) {
            short* pu = (short*)(smem + 98304 + wv * 2048 + u * 1024);
            // P = 2^(S2 - 40): fixed-shift softmax, no max tracking
#pragma unroll
            for (int mt = 0; mt < 2; ++mt) {
                s16x4 pv;
#pragma unroll
                for (int rr = 0; rr < 4; ++rr) {
                    float p = exp2f(ssw[u][mt][rr] - 40.f);
                    ps_[u] += p;
                    pv[rr] = f2bf(p);
                }
                *(s16x4*)(pu + ((mt * 2 + (lg >> 1)) * 16 + lr) * 8 + (lg & 1) * 4) = pv;
            }
            bf16x8 pa = *(const bf16x8*)(pu + l * 8);
#pragma unroll
            for (int dt = 0; dt < 8; ++dt)
                o[u][dt] = __builtin_amdgcn_mfma_f32_16x16x32_bf16(pa, gf[dt], o[u][dt], 0, 0, 0);
        }
    }

    // ---- merge partials (key-group 1 -> 0) via LDS
    __syncthreads();
    float* mg = (float*)smem;
    if (wv >= 4) {
        float* mb = mg + (size_t)((wv - 4) * 64 + l) * 68;
#pragma unroll
        for (int u = 0; u < 2; ++u)
#pragma unroll
            for (int dt = 0; dt < 8; ++dt)
                *(f32x4*)(mb + (u * 8 + dt) * 4) = o[u][dt];
        mb[64] = ps_[0]; mb[65] = ps_[1];
    }
    __syncthreads();
    if (wv < 4) {
        const float* mb = mg + (size_t)(wv * 64 + l) * 68;
#pragma unroll
        for (int u = 0; u < 2; ++u)
#pragma unroll
            for (int dt = 0; dt < 8; ++dt) {
                f32x4 pv = *(const f32x4*)(mb + (u * 8 + dt) * 4);
#pragma unroll
                for (int e = 0; e < 4; ++e) o[u][dt][e] += pv[e];
            }
        ps_[0] += mb[64]; ps_[1] += mb[65];

        short* Zb = Z + (size_t)b * 16 * 4096 * 8;
#pragma unroll
        for (int u = 0; u < 2; ++u) {
            float tot = ps_[u];
            tot += __shfl_xor(tot, 16);
            tot += __shfl_xor(tot, 32);
            float inv = 1.f / tot;
            float invg[4];
#pragma unroll
            for (int rr = 0; rr < 4; ++rr) invg[rr] = __shfl(inv, lg * 4 + rr);
            const int wq = wvl * 2 + u;
#pragma unroll
            for (int dt = 0; dt < 8; ++dt) {
                s16x4 zv;
#pragma unroll
                for (int rr = 0; rr < 4; ++rr) zv[rr] = f2bf(o[u][dt][rr] * invg[rr]);
                size_t g = (size_t)(wq * 2 + (lg >> 1)) * 4096 + s * 128 + dt * 16 + lr;
                *(s16x4*)(Zb + g * 8 + (lg & 1) * 4) = zv;
            }
        }
    }
}

// ---------------------------------------------------------------------------
// Final conv: out[b][256 co][4096 l] = wz @ m3 + bias + x. bf16 wz direct.
// ---------------------------------------------------------------------------
__global__ __launch_bounds__(256)
void conv_fin_k(const short* __restrict__ Z, const short* __restrict__ wzh,
                const float* __restrict__ wzb, const float* __restrict__ x,
                float* __restrict__ out)
{
    const int t  = threadIdx.x;
    const int wv = t >> 6;
    const int l  = t & 63;
    const int lr = l & 15;
    const int lg = l >> 4;
    const int b  = blockIdx.z;
    const int co0 = blockIdx.y * 64 + (wv >> 1) * 32;
    const int l0  = blockIdx.x * 256 + (wv & 1) * 128;

    bf16x8 afr[2][4];
#pragma unroll
    for (int nt = 0; nt < 2; ++nt) {
        int co = co0 + nt * 16 + lr;
#pragma unroll
        for (int kt = 0; kt < 4; ++kt)
            afr[nt][kt] = *(const bf16x8*)(wzh + (size_t)co * 128 + kt * 32 + lg * 8);
    }

    const short* Zb = Z + (size_t)b * 16 * 4096 * 8;
    f32x4 o[2][8];
#pragma unroll
    for (int nt = 0; nt < 2; ++nt)
#pragma unroll
        for (int dt = 0; dt < 8; ++dt)
#pragma unroll
            for (int e = 0; e < 4; ++e) o[nt][dt][e] = 0.f;

#pragma unroll
    for (int dt = 0; dt < 8; ++dt) {
        int lpix = l0 + dt * 16 + lr;
#pragma unroll
        for (int kt = 0; kt < 4; ++kt) {
            bf16x8 bz = *(const bf16x8*)(Zb + ((size_t)(kt * 4 + lg) * 4096 + lpix) * 8);
            o[0][dt] = __builtin_amdgcn_mfma_f32_16x16x32_bf16(afr[0][kt], bz, o[0][dt], 0, 0, 0);
            o[1][dt] = __builtin_amdgcn_mfma_f32_16x16x32_bf16(afr[1][kt], bz, o[1][dt], 0, 0, 0);
        }
    }

#pragma unroll
    for (int nt = 0; nt < 2; ++nt)
#pragma unroll
        for (int rr = 0; rr < 4; ++rr) {
            int co = co0 + nt * 16 + lg * 4 + rr;
            float bv = wzb[co];
            const float* xb = x + ((size_t)b * 256 + co) * 4096;
            float* ob = out + ((size_t)b * 256 + co) * 4096;
#pragma unroll
            for (int dt = 0; dt < 8; ++dt) {
                int lpix = l0 + dt * 16 + lr;
                ob[lpix] = o[nt][dt][rr] + bv + xb[lpix];
            }
        }
}

extern "C" void kernel_launch(void* const* d_in, const int* in_sizes, int n_in,
                              void* d_out, int out_size, void* d_ws, size_t ws_size,
                              hipStream_t stream)
{
    const float* x       = (const float*)d_in[0];
    const float* theta_w = (const float*)d_in[1];
    const float* theta_b = (const float*)d_in[2];
    const float* phi_w   = (const float*)d_in[3];
    const float* phi_b   = (const float*)d_in[4];
    const float* g_w     = (const float*)d_in[5];
    const float* g_b     = (const float*)d_in[6];
    const float* wz_w    = (const float*)d_in[7];
    const float* wz_b    = (const float*)d_in[8];
    float* out = (float*)d_out;

    short* ws      = (short*)d_ws;
    short* theta_h = ws;                         // [B,4096,128]  4194304
    short* phi_h   = theta_h + (size_t)4194304;  // [B,32,4096]   1048576
    short* G_h     = phi_h + (size_t)1048576;    // [B,32,4096]   1048576
    short* Z       = G_h  + (size_t)1048576;     // [B,16,4096,8] 4194304
    short* wh      = Z    + (size_t)4194304;     // 131072 bf16 weights
    short* th_wh = wh;
    short* ph_wh = wh + 32768;
    short* g_wh  = wh + 65536;
    short* wz_wh = wh + 98304;

    wcvt_k<<<dim3(128), 256, 0, stream>>>(theta_w, phi_w, g_w, wz_w, wh);

    front_k<<<dim3(256), 512, 0, stream>>>(x, th_wh, theta_b, ph_wh, phi_b,
                                           g_wh, g_b, theta_h, phi_h, G_h);

    attn_v9<<<dim3(256), 512, 0, stream>>>(theta_h, phi_h, G_h, Z);

    conv_fin_k<<<dim3(16, 4, BATCH), 256, 0, stream>>>(Z, wz_wh, wz_b, x, out);
}

// Round 11
// 89.120 us; speedup vs baseline: 1.2979x; 1.0955x over previous
//
#include <hip/hip_runtime.h>
#include <math.h>

#define BATCH 8
#define CINCH 256
#define CMID  128
#define NPIX  4096   // 64*64
#define MPIX  1024   // 32*32

typedef __attribute__((ext_vector_type(8))) short bf16x8;
typedef __attribute__((ext_vector_type(4))) short s16x4;
typedef __attribute__((ext_vector_type(4))) float f32x4;

static __device__ __forceinline__ short f2bf(float f) {
    unsigned u = __float_as_uint(f);
    u = (u + 0x7fffu + ((u >> 16) & 1u)) >> 16;   // RNE bf16
    return (short)u;
}
static __device__ __forceinline__ float bf2f(short s) {
    return __uint_as_float(((unsigned)(unsigned short)s) << 16);
}

static __device__ __forceinline__ void gl16(const void* g, void* l) {
    __builtin_amdgcn_global_load_lds(
        (const __attribute__((address_space(1))) void*)g,
        (__attribute__((address_space(3))) void*)l, 16, 0, 0);
}

// ---------------------------------------------------------------------------
// Weight f32->bf16 pre-convert.
// theta: rows PERMUTED (dest row R holds src row perm(R)=(R&15)*8+(R>>4)),
//        scaled by log2(e). Net effect: theta_h output comes out channel-
//        LINEAR with packed stores (perm cancels in the epilogue).
// phi, g, wz: LINEAR.
// ---------------------------------------------------------------------------
__global__ __launch_bounds__(256)
void wcvt_k(const float* __restrict__ a, const float* __restrict__ b,
            const float* __restrict__ c, const float* __restrict__ d,
            short* __restrict__ o)
{
    int i = (blockIdx.x * 256 + threadIdx.x) * 4;   // 131072 total
    if (i < 32768) {   // theta: permuted rows + log2e scale
        int cr = i >> 8, col = i & 255;
        int R = (cr & 7) * 16 + (cr >> 3);   // perm(R) = cr
        float4 v = *(const float4*)(a + i);
        s16x4 rv = { f2bf(v.x * 1.44269504f), f2bf(v.y * 1.44269504f),
                     f2bf(v.z * 1.44269504f), f2bf(v.w * 1.44269504f) };
        *(s16x4*)(o + R * 256 + col) = rv;
    } else {
        const float* src; int j;
        if (i < 65536)      { src = b; j = i - 32768; }
        else if (i < 98304) { src = c; j = i - 65536; }
        else                { src = d; j = i - 98304; }
        float4 v = *(const float4*)(src + j);
        s16x4 rv = { f2bf(v.x), f2bf(v.y), f2bf(v.z), f2bf(v.w) };
        *(s16x4*)(o + i) = rv;
    }
}

// ---------------------------------------------------------------------------
// front_k: fused transpose + theta conv + maxpool + phi/g convs.
// (unchanged from round 10 — passing)
// ---------------------------------------------------------------------------
__global__ __launch_bounds__(512)
void front_k(const float* __restrict__ x,
             const short* __restrict__ th_wh, const float* __restrict__ th_b,
             const short* __restrict__ ph_wh, const float* __restrict__ ph_b,
             const short* __restrict__ g_wh,  const float* __restrict__ g_b,
             short* __restrict__ thetaO, short* __restrict__ phiO,
             short* __restrict__ gO)
{
    __shared__ float F[128 * 65];
    __shared__ short X[128 * 264];
    __shared__ short P[32 * 264];

    const int bid = blockIdx.x;
    const int t   = threadIdx.x;
    const int b   = bid & 7;
    const int r   = bid >> 3;
    const int wv  = t >> 6;
    const int l   = t & 63;
    const int lr  = l & 15;
    const int lg  = l >> 4;

    // ---- Phase A: x -> bf16 transposed tile, software-pipelined
    const int hh = wv & 1;
    const int c0 = t >> 7;
    float ra[16], rb[16];
    {
        const float* xb = x + ((size_t)(b * 256)) * 4096 + r * 128;
#pragma unroll
        for (int i = 0; i < 16; ++i)
            ra[i] = xb[(size_t)(c0 + i * 4) * 4096 + hh * 64 + l];
    }
#pragma unroll
    for (int ct = 0; ct < 4; ++ct) {
        if ((ct & 1) == 0) {
#pragma unroll
            for (int i = 0; i < 16; ++i) F[(hh * 64 + l) * 65 + c0 + i * 4] = ra[i];
            if (ct < 3) {
                const float* xb = x + ((size_t)(b * 256 + (ct + 1) * 64)) * 4096 + r * 128;
#pragma unroll
                for (int i = 0; i < 16; ++i)
                    rb[i] = xb[(size_t)(c0 + i * 4) * 4096 + hh * 64 + l];
            }
        } else {
#pragma unroll
            for (int i = 0; i < 16; ++i) F[(hh * 64 + l) * 65 + c0 + i * 4] = rb[i];
            if (ct < 3) {
                const float* xb = x + ((size_t)(b * 256 + (ct + 1) * 64)) * 4096 + r * 128;
#pragma unroll
                for (int i = 0; i < 16; ++i)
                    ra[i] = xb[(size_t)(c0 + i * 4) * 4096 + hh * 64 + l];
            }
        }
        asm volatile("s_waitcnt lgkmcnt(0)" ::: "memory");
        __builtin_amdgcn_s_barrier();
#pragma unroll
        for (int i = 0; i < 16; ++i) {
            int row = wv + i * 8;
            X[row * 264 + ct * 64 + l] = f2bf(F[row * 65 + l]);
        }
        asm volatile("s_waitcnt lgkmcnt(0)" ::: "memory");
        __builtin_amdgcn_s_barrier();
    }

    // ---- Phase B: maxpool into P
#pragma unroll
    for (int i = 0; i < 4; ++i) {
        int slot = i * 512 + t;
        int wp = slot >> 6, c4 = slot & 63;
        s16x4 v0 = *(const s16x4*)(X + (2 * wp) * 264 + c4 * 4);
        s16x4 v1 = *(const s16x4*)(X + (2 * wp + 1) * 264 + c4 * 4);
        s16x4 v2 = *(const s16x4*)(X + (64 + 2 * wp) * 264 + c4 * 4);
        s16x4 v3 = *(const s16x4*)(X + (65 + 2 * wp) * 264 + c4 * 4);
        s16x4 rm;
#pragma unroll
        for (int e = 0; e < 4; ++e) {
            float m = fmaxf(fmaxf(bf2f(v0[e]), bf2f(v1[e])),
                            fmaxf(bf2f(v2[e]), bf2f(v3[e])));
            rm[e] = f2bf(m);
        }
        *(s16x4*)(P + wp * 264 + c4 * 4) = rm;
    }
    __syncthreads();

    // ---- Phase C1: theta conv (permuted weights) -> packed bf16x8 stores
    {
        const int m0 = wv * 16;
        f32x4 o[8];
#pragma unroll
        for (int dt = 0; dt < 8; ++dt)
#pragma unroll
            for (int e = 0; e < 4; ++e) o[dt][e] = 0.f;
        for (int kt = 0; kt < 8; ++kt) {
            bf16x8 a = *(const bf16x8*)(X + (m0 + lr) * 264 + kt * 32 + lg * 8);
#pragma unroll
            for (int dt = 0; dt < 8; ++dt) {
                bf16x8 bv = *(const bf16x8*)(th_wh + (size_t)(dt * 16 + lr) * 256 + kt * 32 + lg * 8);
                o[dt] = __builtin_amdgcn_mfma_f32_16x16x32_bf16(a, bv, o[dt], 0, 0, 0);
            }
        }
        float bvt[8];
#pragma unroll
        for (int dt = 0; dt < 8; ++dt) bvt[dt] = th_b[lr * 8 + dt] * 1.44269504f;
        short* ob = thetaO + (size_t)b * NPIX * 128;
#pragma unroll
        for (int rr = 0; rr < 4; ++rr) {
            int n = r * 128 + m0 + lg * 4 + rr;
            bf16x8 sv;
#pragma unroll
            for (int dt = 0; dt < 8; ++dt) sv[dt] = f2bf(o[dt][rr] + bvt[dt]);
            *(bf16x8*)(ob + (size_t)n * 128 + lr * 8) = sv;
        }
    }

    // ---- Phase C2: phi (waves 0-3, LINEAR weights) / G (waves 4-7)
    {
        const int half = wv & 1;
        const int coH  = (wv >> 1) & 1;
        const short* wsel = ((wv < 4) ? ph_wh : g_wh) + (size_t)coH * 64 * 256;
        const float* bsel = (wv < 4) ? ph_b : g_b;

        f32x4 q[4];
#pragma unroll
        for (int dt = 0; dt < 4; ++dt)
#pragma unroll
            for (int e = 0; e < 4; ++e) q[dt][e] = 0.f;
        for (int kt = 0; kt < 8; ++kt) {
            bf16x8 a = *(const bf16x8*)(P + (half * 16 + lr) * 264 + kt * 32 + lg * 8);
#pragma unroll
            for (int dt = 0; dt < 4; ++dt) {
                bf16x8 bv = *(const bf16x8*)(wsel + (size_t)(dt * 16 + lr) * 256 + kt * 32 + lg * 8);
                q[dt] = __builtin_amdgcn_mfma_f32_16x16x32_bf16(a, bv, q[dt], 0, 0, 0);
            }
        }
        float bv4[4];
#pragma unroll
        for (int dt = 0; dt < 4; ++dt) bv4[dt] = bsel[coH * 64 + dt * 16 + lr];

        if (wv < 4) {
            short* cb = phiO + (size_t)b * 32 * 4096 + (size_t)r * 4096;
#pragma unroll
            for (int rr = 0; rr < 4; ++rr) {
                int mloc = half * 16 + lg * 4 + rr;
                short* cbb = cb + (mloc >> 4) * 512 + (mloc & 15) * 8;
#pragma unroll
                for (int dt = 0; dt < 4; ++dt) {
                    int cc = coH * 64 + dt * 16 + lr;
                    cbb[(cc >> 5) * 1024 + ((cc >> 3) & 3) * 128 + (cc & 7)]
                        = f2bf(q[dt][rr] + bv4[dt]);
                }
            }
        } else {
            short* cb = gO + (size_t)b * 32 * 4096 + (size_t)r * 4096;
            const int keyblk = half * 2 + (lg >> 1);
#pragma unroll
            for (int dt = 0; dt < 4; ++dt) {
                int cc = coH * 64 + dt * 16 + lr;
                s16x4 sv;
#pragma unroll
                for (int rr = 0; rr < 4; ++rr) sv[rr] = f2bf(q[dt][rr] + bv4[dt]);
                *(s16x4*)(cb + (size_t)((cc >> 4) * 64 + keyblk * 16 + (cc & 15)) * 8
                             + (lg & 1) * 4) = sv;
            }
        }
    }
}

// ---------------------------------------------------------------------------
// attn_v10: pair-granular pipeline. 2 chunks per iteration; pair-level
// double-buffer (2 grp x 2 pairbuf x 32KB = 128KB); stage pair pi+1 right
// after iter pi's barrier -> full-iteration load lead time; 8 barriers.
// ---------------------------------------------------------------------------
__global__ __launch_bounds__(512)
void attn_v10(const short* __restrict__ theta, const short* __restrict__ phi_sw,
              const short* __restrict__ G_sw, short* __restrict__ Z)
{
    __shared__ __align__(16) char smem[147456];  // 128KB stage + 16KB P slabs
    const int t   = threadIdx.x;
    const int wv  = t >> 6;
    const int l   = t & 63;
    const int lr  = l & 15;
    const int lg  = l >> 4;
    const int gid = wv >> 2;       // key-group
    const int wvl = wv & 3;        // wave-in-group
    const int bid = blockIdx.x;
    const int b   = bid & 7;       // batch -> XCD
    const int s   = bid >> 3;      // n & 31

    const short* thb = theta + (size_t)b * NPIX * 128;
    const char*  phC = (const char*)phi_sw + (size_t)b * 32 * 8192;
    const char*  gC  = (const char*)G_sw  + (size_t)b * 32 * 8192;
    const int first = gid * 16;

    auto STAGEP = [&](int bufi, int pi) {   // stage pair pi (2 chunks)
#pragma unroll
        for (int sub = 0; sub < 2; ++sub) {
            int chunk = first + pi * 2 + sub;
            const char* ps = phC + (size_t)chunk * 8192 + wvl * 2048 + l * 16;
            const char* gs = gC  + (size_t)chunk * 8192 + wvl * 2048 + l * 16;
            char* base = smem + gid * 65536 + bufi * 32768 + sub * 16384;
            gl16(ps,        base + wvl * 2048);
            gl16(ps + 1024, base + wvl * 2048 + 1024);
            gl16(gs,        base + 8192 + wvl * 2048);
            gl16(gs + 1024, base + 8192 + wvl * 2048 + 1024);
        }
    };

    STAGEP(0, 0);

    // theta B-frags: set u query n = ((wvl*2+u)*16 + lr)*32 + s
    bf16x8 bq[2][4];
#pragma unroll
    for (int u = 0; u < 2; ++u) {
        int n = ((wvl * 2 + u) * 16 + lr) * 32 + s;
#pragma unroll
        for (int kt = 0; kt < 4; ++kt)
            bq[u][kt] = *(const bf16x8*)(thb + (size_t)n * 128 + kt * 32 + lg * 8);
    }

    f32x4 o[2][8];
#pragma unroll
    for (int u = 0; u < 2; ++u)
#pragma unroll
        for (int dt = 0; dt < 8; ++dt)
#pragma unroll
            for (int e = 0; e < 4; ++e) o[u][dt][e] = 0.f;
    float ps_[2] = { 0.f, 0.f };

    for (int pi = 0; pi < 8; ++pi) {
        asm volatile("s_waitcnt vmcnt(0)" ::: "memory");
        __builtin_amdgcn_s_barrier();           // raw: stage loads below span iter
        if (pi < 7) STAGEP((pi + 1) & 1, pi + 1);

#pragma unroll
        for (int sub = 0; sub < 2; ++sub) {
            const short* pb = (const short*)(smem + gid * 65536 + (pi & 1) * 32768
                                             + sub * 16384);
            const short* gb = pb + 4096;

            // ---- S^T = mfma(A=phi, B=theta): D[key][query col=lr]
            f32x4 ssw[2][2];
#pragma unroll
            for (int u = 0; u < 2; ++u)
#pragma unroll
                for (int mt = 0; mt < 2; ++mt)
#pragma unroll
                    for (int e = 0; e < 4; ++e) ssw[u][mt][e] = 0.f;
#pragma unroll
            for (int kt = 0; kt < 4; ++kt) {
                bf16x8 a0 = *(const bf16x8*)(pb + ((kt * 2 + 0) * 64 + l) * 8);
                bf16x8 a1 = *(const bf16x8*)(pb + ((kt * 2 + 1) * 64 + l) * 8);
#pragma unroll
                for (int u = 0; u < 2; ++u) {
                    ssw[u][0] = __builtin_amdgcn_mfma_f32_16x16x32_bf16(a0, bq[u][kt], ssw[u][0], 0, 0, 0);
                    ssw[u][1] = __builtin_amdgcn_mfma_f32_16x16x32_bf16(a1, bq[u][kt], ssw[u][1], 0, 0, 0);
                }
            }

            bf16x8 gf[8];
#pragma unroll
            for (int dt = 0; dt < 8; ++dt)
                gf[dt] = *(const bf16x8*)(gb + (dt * 64 + l) * 8);

#pragma unroll
            for (int u = 0; u < 2; ++u) {
                short* pu = (short*)(smem + 131072 + wv * 2048 + u * 1024);
                // P = 2^(S2 - 40): fixed-shift softmax, no max tracking
#pragma unroll
                for (int mt = 0; mt < 2; ++mt) {
                    s16x4 pv;
#pragma unroll
                    for (int rr = 0; rr < 4; ++rr) {
                        float p = exp2f(ssw[u][mt][rr] - 40.f);
                        ps_[u] += p;
                        pv[rr] = f2bf(p);
                    }
                    *(s16x4*)(pu + ((mt * 2 + (lg >> 1)) * 16 + lr) * 8 + (lg & 1) * 4) = pv;
                }
                bf16x8 pa = *(const bf16x8*)(pu + l * 8);
#pragma unroll
                for (int dt = 0; dt < 8; ++dt)
                    o[u][dt] = __builtin_amdgcn_mfma_f32_16x16x32_bf16(pa, gf[dt], o[u][dt], 0, 0, 0);
            }
        }
    }

    // ---- merge partials (key-group 1 -> 0) via LDS
    __syncthreads();
    float* mg = (float*)smem;
    if (wv >= 4) {
        float* mb = mg + (size_t)((wv - 4) * 64 + l) * 68;
#pragma unroll
        for (int u = 0; u < 2; ++u)
#pragma unroll
            for (int dt = 0; dt < 8; ++dt)
                *(f32x4*)(mb + (u * 8 + dt) * 4) = o[u][dt];
        mb[64] = ps_[0]; mb[65] = ps_[1];
    }
    __syncthreads();
    if (wv < 4) {
        const float* mb = mg + (size_t)(wv * 64 + l) * 68;
#pragma unroll
        for (int u = 0; u < 2; ++u)
#pragma unroll
            for (int dt = 0; dt < 8; ++dt) {
                f32x4 pv = *(const f32x4*)(mb + (u * 8 + dt) * 4);
#pragma unroll
                for (int e = 0; e < 4; ++e) o[u][dt][e] += pv[e];
            }
        ps_[0] += mb[64]; ps_[1] += mb[65];

        short* Zb = Z + (size_t)b * 16 * 4096 * 8;
#pragma unroll
        for (int u = 0; u < 2; ++u) {
            float tot = ps_[u];
            tot += __shfl_xor(tot, 16);
            tot += __shfl_xor(tot, 32);
            float inv = 1.f / tot;
            float invg[4];
#pragma unroll
            for (int rr = 0; rr < 4; ++rr) invg[rr] = __shfl(inv, lg * 4 + rr);
            const int wq = wvl * 2 + u;
#pragma unroll
            for (int dt = 0; dt < 8; ++dt) {
                s16x4 zv;
#pragma unroll
                for (int rr = 0; rr < 4; ++rr) zv[rr] = f2bf(o[u][dt][rr] * invg[rr]);
                size_t g = (size_t)(wq * 2 + (lg >> 1)) * 4096 + s * 128 + dt * 16 + lr;
                *(s16x4*)(Zb + g * 8 + (lg & 1) * 4) = zv;
            }
        }
    }
}

// ---------------------------------------------------------------------------
// Final conv: out[b][256 co][4096 l] = wz @ m3 + bias + x. bf16 wz direct.
// 1024 blocks (32,4,8), wave = 32 co x 64 l -> 4 waves/SIMD.
// ---------------------------------------------------------------------------
__global__ __launch_bounds__(256)
void conv_fin_k(const short* __restrict__ Z, const short* __restrict__ wzh,
                const float* __restrict__ wzb, const float* __restrict__ x,
                float* __restrict__ out)
{
    const int t  = threadIdx.x;
    const int wv = t >> 6;
    const int l  = t & 63;
    const int lr = l & 15;
    const int lg = l >> 4;
    const int b  = blockIdx.z;
    const int co0 = blockIdx.y * 64 + (wv >> 1) * 32;
    const int l0  = blockIdx.x * 128 + (wv & 1) * 64;

    bf16x8 afr[2][4];
#pragma unroll
    for (int nt = 0; nt < 2; ++nt) {
        int co = co0 + nt * 16 + lr;
#pragma unroll
        for (int kt = 0; kt < 4; ++kt)
            afr[nt][kt] = *(const bf16x8*)(wzh + (size_t)co * 128 + kt * 32 + lg * 8);
    }

    const short* Zb = Z + (size_t)b * 16 * 4096 * 8;
    f32x4 o[2][4];
#pragma unroll
    for (int nt = 0; nt < 2; ++nt)
#pragma unroll
        for (int dt = 0; dt < 4; ++dt)
#pragma unroll
            for (int e = 0; e < 4; ++e) o[nt][dt][e] = 0.f;

#pragma unroll
    for (int dt = 0; dt < 4; ++dt) {
        int lpix = l0 + dt * 16 + lr;
#pragma unroll
        for (int kt = 0; kt < 4; ++kt) {
            bf16x8 bz = *(const bf16x8*)(Zb + ((size_t)(kt * 4 + lg) * 4096 + lpix) * 8);
            o[0][dt] = __builtin_amdgcn_mfma_f32_16x16x32_bf16(afr[0][kt], bz, o[0][dt], 0, 0, 0);
            o[1][dt] = __builtin_amdgcn_mfma_f32_16x16x32_bf16(afr[1][kt], bz, o[1][dt], 0, 0, 0);
        }
    }

#pragma unroll
    for (int nt = 0; nt < 2; ++nt)
#pragma unroll
        for (int rr = 0; rr < 4; ++rr) {
            int co = co0 + nt * 16 + lg * 4 + rr;
            float bv = wzb[co];
            const float* xb = x + ((size_t)b * 256 + co) * 4096;
            float* ob = out + ((size_t)b * 256 + co) * 4096;
#pragma unroll
            for (int dt = 0; dt < 4; ++dt) {
                int lpix = l0 + dt * 16 + lr;
                ob[lpix] = o[nt][dt][rr] + bv + xb[lpix];
            }
        }
}

extern "C" void kernel_launch(void* const* d_in, const int* in_sizes, int n_in,
                              void* d_out, int out_size, void* d_ws, size_t ws_size,
                              hipStream_t stream)
{
    const float* x       = (const float*)d_in[0];
    const float* theta_w = (const float*)d_in[1];
    const float* theta_b = (const float*)d_in[2];
    const float* phi_w   = (const float*)d_in[3];
    const float* phi_b   = (const float*)d_in[4];
    const float* g_w     = (const float*)d_in[5];
    const float* g_b     = (const float*)d_in[6];
    const float* wz_w    = (const float*)d_in[7];
    const float* wz_b    = (const float*)d_in[8];
    float* out = (float*)d_out;

    short* ws      = (short*)d_ws;
    short* theta_h = ws;                         // [B,4096,128]  4194304
    short* phi_h   = theta_h + (size_t)4194304;  // [B,32,4096]   1048576
    short* G_h     = phi_h + (size_t)1048576;    // [B,32,4096]   1048576
    short* Z       = G_h  + (size_t)1048576;     // [B,16,4096,8] 4194304
    short* wh      = Z    + (size_t)4194304;     // 131072 bf16 weights
    short* th_wh = wh;
    short* ph_wh = wh + 32768;
    short* g_wh  = wh + 65536;
    short* wz_wh = wh + 98304;

    wcvt_k<<<dim3(128), 256, 0, stream>>>(theta_w, phi_w, g_w, wz_w, wh);

    front_k<<<dim3(256), 512, 0, stream>>>(x, th_wh, theta_b, ph_wh, phi_b,
                                           g_wh, g_b, theta_h, phi_h, G_h);

    attn_v10<<<dim3(256), 512, 0, stream>>>(theta_h, phi_h, G_h, Z);

    conv_fin_k<<<dim3(32, 4, BATCH), 256, 0, stream>>>(Z, wz_wh, wz_b, x, out);
}

// Round 12
// 73.276 us; speedup vs baseline: 1.5785x; 1.2162x over previous
//
#include <hip/hip_runtime.h>
#include <math.h>

#define BATCH 8
#define CINCH 256
#define CMID  128
#define NPIX  4096   // 64*64
#define MPIX  1024   // 32*32

typedef __attribute__((ext_vector_type(8))) short bf16x8;
typedef __attribute__((ext_vector_type(4))) short s16x4;
typedef __attribute__((ext_vector_type(4))) float f32x4;

static __device__ __forceinline__ short f2bf(float f) {
    unsigned u = __float_as_uint(f);
    u = (u + 0x7fffu + ((u >> 16) & 1u)) >> 16;   // RNE bf16
    return (short)u;
}
static __device__ __forceinline__ float bf2f(short s) {
    return __uint_as_float(((unsigned)(unsigned short)s) << 16);
}

static __device__ __forceinline__ void gl16(const void* g, void* l) {
    __builtin_amdgcn_global_load_lds(
        (const __attribute__((address_space(1))) void*)g,
        (__attribute__((address_space(3))) void*)l, 16, 0, 0);
}

// ---------------------------------------------------------------------------
// Weight f32->bf16 pre-convert.
// theta: rows PERMUTED (dest row R holds src row perm(R)=(R&15)*8+(R>>4)),
//        scaled by log2(e). phi, g, wz: LINEAR.
// ---------------------------------------------------------------------------
__global__ __launch_bounds__(256)
void wcvt_k(const float* __restrict__ a, const float* __restrict__ b,
            const float* __restrict__ c, const float* __restrict__ d,
            short* __restrict__ o)
{
    int i = (blockIdx.x * 256 + threadIdx.x) * 4;   // 131072 total
    if (i < 32768) {   // theta: permuted rows + log2e scale
        int cr = i >> 8, col = i & 255;
        int R = (cr & 7) * 16 + (cr >> 3);   // perm(R) = cr
        float4 v = *(const float4*)(a + i);
        s16x4 rv = { f2bf(v.x * 1.44269504f), f2bf(v.y * 1.44269504f),
                     f2bf(v.z * 1.44269504f), f2bf(v.w * 1.44269504f) };
        *(s16x4*)(o + R * 256 + col) = rv;
    } else {
        const float* src; int j;
        if (i < 65536)      { src = b; j = i - 32768; }
        else if (i < 98304) { src = c; j = i - 65536; }
        else                { src = d; j = i - 98304; }
        float4 v = *(const float4*)(src + j);
        s16x4 rv = { f2bf(v.x), f2bf(v.y), f2bf(v.z), f2bf(v.w) };
        *(s16x4*)(o + i) = rv;
    }
}

// ---------------------------------------------------------------------------
// front_k: fused transpose + theta conv + maxpool + phi/g convs. (unchanged)
// ---------------------------------------------------------------------------
__global__ __launch_bounds__(512)
void front_k(const float* __restrict__ x,
             const short* __restrict__ th_wh, const float* __restrict__ th_b,
             const short* __restrict__ ph_wh, const float* __restrict__ ph_b,
             const short* __restrict__ g_wh,  const float* __restrict__ g_b,
             short* __restrict__ thetaO, short* __restrict__ phiO,
             short* __restrict__ gO)
{
    __shared__ float F[128 * 65];
    __shared__ short X[128 * 264];
    __shared__ short P[32 * 264];

    const int bid = blockIdx.x;
    const int t   = threadIdx.x;
    const int b   = bid & 7;
    const int r   = bid >> 3;
    const int wv  = t >> 6;
    const int l   = t & 63;
    const int lr  = l & 15;
    const int lg  = l >> 4;

    // ---- Phase A: x -> bf16 transposed tile, software-pipelined
    const int hh = wv & 1;
    const int c0 = t >> 7;
    float ra[16], rb[16];
    {
        const float* xb = x + ((size_t)(b * 256)) * 4096 + r * 128;
#pragma unroll
        for (int i = 0; i < 16; ++i)
            ra[i] = xb[(size_t)(c0 + i * 4) * 4096 + hh * 64 + l];
    }
#pragma unroll
    for (int ct = 0; ct < 4; ++ct) {
        if ((ct & 1) == 0) {
#pragma unroll
            for (int i = 0; i < 16; ++i) F[(hh * 64 + l) * 65 + c0 + i * 4] = ra[i];
            if (ct < 3) {
                const float* xb = x + ((size_t)(b * 256 + (ct + 1) * 64)) * 4096 + r * 128;
#pragma unroll
                for (int i = 0; i < 16; ++i)
                    rb[i] = xb[(size_t)(c0 + i * 4) * 4096 + hh * 64 + l];
            }
        } else {
#pragma unroll
            for (int i = 0; i < 16; ++i) F[(hh * 64 + l) * 65 + c0 + i * 4] = rb[i];
            if (ct < 3) {
                const float* xb = x + ((size_t)(b * 256 + (ct + 1) * 64)) * 4096 + r * 128;
#pragma unroll
                for (int i = 0; i < 16; ++i)
                    ra[i] = xb[(size_t)(c0 + i * 4) * 4096 + hh * 64 + l];
            }
        }
        asm volatile("s_waitcnt lgkmcnt(0)" ::: "memory");
        __builtin_amdgcn_s_barrier();
#pragma unroll
        for (int i = 0; i < 16; ++i) {
            int row = wv + i * 8;
            X[row * 264 + ct * 64 + l] = f2bf(F[row * 65 + l]);
        }
        asm volatile("s_waitcnt lgkmcnt(0)" ::: "memory");
        __builtin_amdgcn_s_barrier();
    }

    // ---- Phase B: maxpool into P
#pragma unroll
    for (int i = 0; i < 4; ++i) {
        int slot = i * 512 + t;
        int wp = slot >> 6, c4 = slot & 63;
        s16x4 v0 = *(const s16x4*)(X + (2 * wp) * 264 + c4 * 4);
        s16x4 v1 = *(const s16x4*)(X + (2 * wp + 1) * 264 + c4 * 4);
        s16x4 v2 = *(const s16x4*)(X + (64 + 2 * wp) * 264 + c4 * 4);
        s16x4 v3 = *(const s16x4*)(X + (65 + 2 * wp) * 264 + c4 * 4);
        s16x4 rm;
#pragma unroll
        for (int e = 0; e < 4; ++e) {
            float m = fmaxf(fmaxf(bf2f(v0[e]), bf2f(v1[e])),
                            fmaxf(bf2f(v2[e]), bf2f(v3[e])));
            rm[e] = f2bf(m);
        }
        *(s16x4*)(P + wp * 264 + c4 * 4) = rm;
    }
    __syncthreads();

    // ---- Phase C1: theta conv (permuted weights) -> packed bf16x8 stores
    {
        const int m0 = wv * 16;
        f32x4 o[8];
#pragma unroll
        for (int dt = 0; dt < 8; ++dt)
#pragma unroll
            for (int e = 0; e < 4; ++e) o[dt][e] = 0.f;
        for (int kt = 0; kt < 8; ++kt) {
            bf16x8 a = *(const bf16x8*)(X + (m0 + lr) * 264 + kt * 32 + lg * 8);
#pragma unroll
            for (int dt = 0; dt < 8; ++dt) {
                bf16x8 bv = *(const bf16x8*)(th_wh + (size_t)(dt * 16 + lr) * 256 + kt * 32 + lg * 8);
                o[dt] = __builtin_amdgcn_mfma_f32_16x16x32_bf16(a, bv, o[dt], 0, 0, 0);
            }
        }
        float bvt[8];
#pragma unroll
        for (int dt = 0; dt < 8; ++dt) bvt[dt] = th_b[lr * 8 + dt] * 1.44269504f;
        short* ob = thetaO + (size_t)b * NPIX * 128;
#pragma unroll
        for (int rr = 0; rr < 4; ++rr) {
            int n = r * 128 + m0 + lg * 4 + rr;
            bf16x8 sv;
#pragma unroll
            for (int dt = 0; dt < 8; ++dt) sv[dt] = f2bf(o[dt][rr] + bvt[dt]);
            *(bf16x8*)(ob + (size_t)n * 128 + lr * 8) = sv;
        }
    }

    // ---- Phase C2: phi (waves 0-3, LINEAR weights) / G (waves 4-7)
    {
        const int half = wv & 1;
        const int coH  = (wv >> 1) & 1;
        const short* wsel = ((wv < 4) ? ph_wh : g_wh) + (size_t)coH * 64 * 256;
        const float* bsel = (wv < 4) ? ph_b : g_b;

        f32x4 q[4];
#pragma unroll
        for (int dt = 0; dt < 4; ++dt)
#pragma unroll
            for (int e = 0; e < 4; ++e) q[dt][e] = 0.f;
        for (int kt = 0; kt < 8; ++kt) {
            bf16x8 a = *(const bf16x8*)(P + (half * 16 + lr) * 264 + kt * 32 + lg * 8);
#pragma unroll
            for (int dt = 0; dt < 4; ++dt) {
                bf16x8 bv = *(const bf16x8*)(wsel + (size_t)(dt * 16 + lr) * 256 + kt * 32 + lg * 8);
                q[dt] = __builtin_amdgcn_mfma_f32_16x16x32_bf16(a, bv, q[dt], 0, 0, 0);
            }
        }
        float bv4[4];
#pragma unroll
        for (int dt = 0; dt < 4; ++dt) bv4[dt] = bsel[coH * 64 + dt * 16 + lr];

        if (wv < 4) {
            short* cb = phiO + (size_t)b * 32 * 4096 + (size_t)r * 4096;
#pragma unroll
            for (int rr = 0; rr < 4; ++rr) {
                int mloc = half * 16 + lg * 4 + rr;
                short* cbb = cb + (mloc >> 4) * 512 + (mloc & 15) * 8;
#pragma unroll
                for (int dt = 0; dt < 4; ++dt) {
                    int cc = coH * 64 + dt * 16 + lr;
                    cbb[(cc >> 5) * 1024 + ((cc >> 3) & 3) * 128 + (cc & 7)]
                        = f2bf(q[dt][rr] + bv4[dt]);
                }
            }
        } else {
            short* cb = gO + (size_t)b * 32 * 4096 + (size_t)r * 4096;
            const int keyblk = half * 2 + (lg >> 1);
#pragma unroll
            for (int dt = 0; dt < 4; ++dt) {
                int cc = coH * 64 + dt * 16 + lr;
                s16x4 sv;
#pragma unroll
                for (int rr = 0; rr < 4; ++rr) sv[rr] = f2bf(q[dt][rr] + bv4[dt]);
                *(s16x4*)(cb + (size_t)((cc >> 4) * 64 + keyblk * 16 + (cc & 15)) * 8
                             + (lg & 1) * 4) = sv;
            }
        }
    }
}

// ---------------------------------------------------------------------------
// attn_fz: attention + FUSED final conv. Block (b, s) computes all queries
// n = s (mod 32) = the complete m3 panel [:, s*128..s*128+128), stores it to
// LDS in conv_fin's B-frag granule order, then all 8 waves run the final
// GEMM (A = wz bf16 L2-hot) + bias + x residual -> out. No Z global buffer.
// ---------------------------------------------------------------------------
__global__ __launch_bounds__(512)
void attn_fz(const short* __restrict__ theta, const short* __restrict__ phi_sw,
             const short* __restrict__ G_sw, const short* __restrict__ wzh,
             const float* __restrict__ wzb, const float* __restrict__ x,
             float* __restrict__ out)
{
    __shared__ __align__(16) char smem[147456];  // 128KB stage + 16KB P slabs
    const int t   = threadIdx.x;
    const int wv  = t >> 6;
    const int l   = t & 63;
    const int lr  = l & 15;
    const int lg  = l >> 4;
    const int gid = wv >> 2;       // key-group
    const int wvl = wv & 3;        // wave-in-group
    const int bid = blockIdx.x;
    const int b   = bid & 7;       // batch -> XCD
    const int s   = bid >> 3;      // n & 31

    const short* thb = theta + (size_t)b * NPIX * 128;
    const char*  phC = (const char*)phi_sw + (size_t)b * 32 * 8192;
    const char*  gC  = (const char*)G_sw  + (size_t)b * 32 * 8192;
    const int first = gid * 16;

    auto STAGEP = [&](int bufi, int pi) {   // stage pair pi (2 chunks)
#pragma unroll
        for (int sub = 0; sub < 2; ++sub) {
            int chunk = first + pi * 2 + sub;
            const char* ps = phC + (size_t)chunk * 8192 + wvl * 2048 + l * 16;
            const char* gs = gC  + (size_t)chunk * 8192 + wvl * 2048 + l * 16;
            char* base = smem + gid * 65536 + bufi * 32768 + sub * 16384;
            gl16(ps,        base + wvl * 2048);
            gl16(ps + 1024, base + wvl * 2048 + 1024);
            gl16(gs,        base + 8192 + wvl * 2048);
            gl16(gs + 1024, base + 8192 + wvl * 2048 + 1024);
        }
    };

    STAGEP(0, 0);

    // theta B-frags: set u query n = ((wvl*2+u)*16 + lr)*32 + s
    bf16x8 bq[2][4];
#pragma unroll
    for (int u = 0; u < 2; ++u) {
        int n = ((wvl * 2 + u) * 16 + lr) * 32 + s;
#pragma unroll
        for (int kt = 0; kt < 4; ++kt)
            bq[u][kt] = *(const bf16x8*)(thb + (size_t)n * 128 + kt * 32 + lg * 8);
    }

    f32x4 o[2][8];
#pragma unroll
    for (int u = 0; u < 2; ++u)
#pragma unroll
        for (int dt = 0; dt < 8; ++dt)
#pragma unroll
            for (int e = 0; e < 4; ++e) o[u][dt][e] = 0.f;
    float ps_[2] = { 0.f, 0.f };

    for (int pi = 0; pi < 8; ++pi) {
        asm volatile("s_waitcnt vmcnt(0)" ::: "memory");
        __builtin_amdgcn_s_barrier();           // raw: stage loads below span iter
        if (pi < 7) STAGEP((pi + 1) & 1, pi + 1);

#pragma unroll
        for (int sub = 0; sub < 2; ++sub) {
            const short* pb = (const short*)(smem + gid * 65536 + (pi & 1) * 32768
                                             + sub * 16384);
            const short* gb = pb + 4096;

            // ---- S^T = mfma(A=phi, B=theta): D[key][query col=lr]
            f32x4 ssw[2][2];
#pragma unroll
            for (int u = 0; u < 2; ++u)
#pragma unroll
                for (int mt = 0; mt < 2; ++mt)
#pragma unroll
                    for (int e = 0; e < 4; ++e) ssw[u][mt][e] = 0.f;
#pragma unroll
            for (int kt = 0; kt < 4; ++kt) {
                bf16x8 a0 = *(const bf16x8*)(pb + ((kt * 2 + 0) * 64 + l) * 8);
                bf16x8 a1 = *(const bf16x8*)(pb + ((kt * 2 + 1) * 64 + l) * 8);
#pragma unroll
                for (int u = 0; u < 2; ++u) {
                    ssw[u][0] = __builtin_amdgcn_mfma_f32_16x16x32_bf16(a0, bq[u][kt], ssw[u][0], 0, 0, 0);
                    ssw[u][1] = __builtin_amdgcn_mfma_f32_16x16x32_bf16(a1, bq[u][kt], ssw[u][1], 0, 0, 0);
                }
            }

            bf16x8 gf[8];
#pragma unroll
            for (int dt = 0; dt < 8; ++dt)
                gf[dt] = *(const bf16x8*)(gb + (dt * 64 + l) * 8);

#pragma unroll
            for (int u = 0; u < 2; ++u) {
                short* pu = (short*)(smem + 131072 + wv * 2048 + u * 1024);
                // P = 2^(S2 - 40): fixed-shift softmax
#pragma unroll
                for (int mt = 0; mt < 2; ++mt) {
                    s16x4 pv;
#pragma unroll
                    for (int rr = 0; rr < 4; ++rr) {
                        float p = exp2f(ssw[u][mt][rr] - 40.f);
                        ps_[u] += p;
                        pv[rr] = f2bf(p);
                    }
                    *(s16x4*)(pu + ((mt * 2 + (lg >> 1)) * 16 + lr) * 8 + (lg & 1) * 4) = pv;
                }
                bf16x8 pa = *(const bf16x8*)(pu + l * 8);
#pragma unroll
                for (int dt = 0; dt < 8; ++dt)
                    o[u][dt] = __builtin_amdgcn_mfma_f32_16x16x32_bf16(pa, gf[dt], o[u][dt], 0, 0, 0);
            }
        }
    }

    // ---- merge partials (key-group 1 -> 0) via LDS
    __syncthreads();
    float* mg = (float*)smem;
    short* m3l = (short*)(smem + 73728);    // m3 panel [16 granule-rows][128 pix][8]
    if (wv >= 4) {
        float* mb = mg + (size_t)((wv - 4) * 64 + l) * 68;
#pragma unroll
        for (int u = 0; u < 2; ++u)
#pragma unroll
            for (int dt = 0; dt < 8; ++dt)
                *(f32x4*)(mb + (u * 8 + dt) * 4) = o[u][dt];
        mb[64] = ps_[0]; mb[65] = ps_[1];
    }
    __syncthreads();
    if (wv < 4) {
        const float* mb = mg + (size_t)(wv * 64 + l) * 68;
#pragma unroll
        for (int u = 0; u < 2; ++u)
#pragma unroll
            for (int dt = 0; dt < 8; ++dt) {
                f32x4 pv = *(const f32x4*)(mb + (u * 8 + dt) * 4);
#pragma unroll
                for (int e = 0; e < 4; ++e) o[u][dt][e] += pv[e];
            }
        ps_[0] += mb[64]; ps_[1] += mb[65];

        // normalize + store m3 panel to LDS (conv B-frag granule order)
#pragma unroll
        for (int u = 0; u < 2; ++u) {
            float tot = ps_[u];
            tot += __shfl_xor(tot, 16);
            tot += __shfl_xor(tot, 32);
            float inv = 1.f / tot;
            float invg[4];
#pragma unroll
            for (int rr = 0; rr < 4; ++rr) invg[rr] = __shfl(inv, lg * 4 + rr);
            const int cmb = (wvl * 2 + u) * 2 + (lg >> 1);   // granule row 0..15
#pragma unroll
            for (int dt = 0; dt < 8; ++dt) {
                s16x4 zv;
#pragma unroll
                for (int rr = 0; rr < 4; ++rr) zv[rr] = f2bf(o[u][dt][rr] * invg[rr]);
                *(s16x4*)(m3l + (size_t)(cmb * 128 + dt * 16 + lr) * 8 + (lg & 1) * 4) = zv;
            }
        }
    }
    __syncthreads();

    // ---- fused final conv: wave wv -> co [wv*32, wv*32+32), 128 pixels
    {
        const int co0 = wv * 32;
        bf16x8 afr[2][4];
#pragma unroll
        for (int nt = 0; nt < 2; ++nt) {
            int co = co0 + nt * 16 + lr;
#pragma unroll
            for (int kt = 0; kt < 4; ++kt)
                afr[nt][kt] = *(const bf16x8*)(wzh + (size_t)co * 128 + kt * 32 + lg * 8);
        }
        f32x4 oc[2][8];
#pragma unroll
        for (int nt = 0; nt < 2; ++nt)
#pragma unroll
            for (int dt = 0; dt < 8; ++dt)
#pragma unroll
                for (int e = 0; e < 4; ++e) oc[nt][dt][e] = 0.f;

#pragma unroll
        for (int dt = 0; dt < 8; ++dt) {
#pragma unroll
            for (int kt = 0; kt < 4; ++kt) {
                bf16x8 bz = *(const bf16x8*)(m3l + (size_t)((kt * 4 + lg) * 128 + dt * 16 + lr) * 8);
                oc[0][dt] = __builtin_amdgcn_mfma_f32_16x16x32_bf16(afr[0][kt], bz, oc[0][dt], 0, 0, 0);
                oc[1][dt] = __builtin_amdgcn_mfma_f32_16x16x32_bf16(afr[1][kt], bz, oc[1][dt], 0, 0, 0);
            }
        }

#pragma unroll
        for (int nt = 0; nt < 2; ++nt)
#pragma unroll
            for (int rr = 0; rr < 4; ++rr) {
                int co = co0 + nt * 16 + lg * 4 + rr;
                float bv = wzb[co];
                const float* xb = x + ((size_t)b * 256 + co) * 4096 + s * 128;
                float* ob = out + ((size_t)b * 256 + co) * 4096 + s * 128;
#pragma unroll
                for (int dt = 0; dt < 8; ++dt) {
                    int lp = dt * 16 + lr;
                    ob[lp] = oc[nt][dt][rr] + bv + xb[lp];
                }
            }
    }
}

extern "C" void kernel_launch(void* const* d_in, const int* in_sizes, int n_in,
                              void* d_out, int out_size, void* d_ws, size_t ws_size,
                              hipStream_t stream)
{
    const float* x       = (const float*)d_in[0];
    const float* theta_w = (const float*)d_in[1];
    const float* theta_b = (const float*)d_in[2];
    const float* phi_w   = (const float*)d_in[3];
    const float* phi_b   = (const float*)d_in[4];
    const float* g_w     = (const float*)d_in[5];
    const float* g_b     = (const float*)d_in[6];
    const float* wz_w    = (const float*)d_in[7];
    const float* wz_b    = (const float*)d_in[8];
    float* out = (float*)d_out;

    short* ws      = (short*)d_ws;
    short* theta_h = ws;                         // [B,4096,128]  4194304
    short* phi_h   = theta_h + (size_t)4194304;  // [B,32,4096]   1048576
    short* G_h     = phi_h + (size_t)1048576;    // [B,32,4096]   1048576
    short* wh      = G_h  + (size_t)1048576;     // 131072 bf16 weights
    short* th_wh = wh;
    short* ph_wh = wh + 32768;
    short* g_wh  = wh + 65536;
    short* wz_wh = wh + 98304;

    wcvt_k<<<dim3(128), 256, 0, stream>>>(theta_w, phi_w, g_w, wz_w, wh);

    front_k<<<dim3(256), 512, 0, stream>>>(x, th_wh, theta_b, ph_wh, phi_b,
                                           g_wh, g_b, theta_h, phi_h, G_h);

    attn_fz<<<dim3(256), 512, 0, stream>>>(theta_h, phi_h, G_h,
                                           wz_wh, wz_b, x, out);
}